// Round 3
// baseline (35557.019 us; speedup 1.0000x reference)
//
#include <hip/hip_runtime.h>

#define NVOX (128*128*128)
#define NK 45
#define NSL 48

// ---------------------------------------------------------------------------
__device__ __forceinline__ int xcc_id() {
    int x;
    asm volatile("s_getreg_b32 %0, hwreg(HW_REG_XCC_ID)" : "=s"(x));
    return x & 7;
}

// L2-local (XCD-scope) fp32 atomic add: no sc1 -> executes in the issuing
// XCD's L2. Only valid when all writers of the target line are on this XCD.
template<bool L2LOCAL>
__device__ __forceinline__ void atom_add(float* p, float v) {
    if (L2LOCAL)
        asm volatile("global_atomic_add_f32 %0, %1, off" :: "v"(p), "v"(v) : "memory");
    else
        unsafeAtomicAdd(p, v);
}

// ---------------------------------------------------------------------------
// trilinear gather with reference semantics (out-of-bounds corners contribute 0)
__device__ __forceinline__ float trilerp_gather(const float* __restrict__ v,
                                                float x, float y, float z)
{
    float x0f = floorf(x), y0f = floorf(y), z0f = floorf(z);
    int x0 = (int)x0f, y0 = (int)y0f, z0 = (int)z0f;
    float fx = x - x0f, fy = y - y0f, fz = z - z0f;

    if (((unsigned)x0 < 127u) & ((unsigned)y0 < 127u) & ((unsigned)z0 < 127u)) {
        const float* p = v + z0*16384 + y0*128 + x0;
        float v000 = p[0],     v001 = p[1];
        float v010 = p[128],   v011 = p[129];
        float v100 = p[16384], v101 = p[16385];
        float v110 = p[16512], v111 = p[16513];
        float c00 = v000 + fx*(v001 - v000);
        float c01 = v010 + fx*(v011 - v010);
        float c10 = v100 + fx*(v101 - v100);
        float c11 = v110 + fx*(v111 - v110);
        float c0  = c00 + fy*(c01 - c00);
        float c1  = c10 + fy*(c11 - c10);
        return c0 + fz*(c1 - c0);
    }
    if (x0 < -1 || x0 > 127 || y0 < -1 || y0 > 127 || z0 < -1 || z0 > 127)
        return 0.f;
    float acc = 0.f;
#pragma unroll
    for (int dz = 0; dz < 2; ++dz) {
        int zi = z0 + dz;
        if ((unsigned)zi >= 128u) continue;
        float wz = dz ? fz : 1.f - fz;
#pragma unroll
        for (int dy = 0; dy < 2; ++dy) {
            int yi = y0 + dy;
            if ((unsigned)yi >= 128u) continue;
            float wy = dy ? fy : 1.f - fy;
#pragma unroll
            for (int dx = 0; dx < 2; ++dx) {
                int xi = x0 + dx;
                if ((unsigned)xi >= 128u) continue;
                float wx = dx ? fx : 1.f - fx;
                acc += wz*wy*wx * v[zi*16384 + yi*128 + xi];
            }
        }
    }
    return acc;
}

template<bool L2LOCAL>
__device__ __forceinline__ void trilerp_splat(float* __restrict__ v,
                                              float x, float y, float z, float val)
{
    float x0f = floorf(x), y0f = floorf(y), z0f = floorf(z);
    int x0 = (int)x0f, y0 = (int)y0f, z0 = (int)z0f;
    float fx = x - x0f, fy = y - y0f, fz = z - z0f;

    if (((unsigned)x0 < 127u) & ((unsigned)y0 < 127u) & ((unsigned)z0 < 127u)) {
        float* p = v + z0*16384 + y0*128 + x0;
        float wx1 = fx, wx0 = 1.f - fx;
        float wy1 = fy, wy0 = 1.f - fy;
        float wz1 = fz, wz0 = 1.f - fz;
        atom_add<L2LOCAL>(p,         val*wz0*wy0*wx0);
        atom_add<L2LOCAL>(p+1,       val*wz0*wy0*wx1);
        atom_add<L2LOCAL>(p+128,     val*wz0*wy1*wx0);
        atom_add<L2LOCAL>(p+129,     val*wz0*wy1*wx1);
        atom_add<L2LOCAL>(p+16384,   val*wz1*wy0*wx0);
        atom_add<L2LOCAL>(p+16385,   val*wz1*wy0*wx1);
        atom_add<L2LOCAL>(p+16512,   val*wz1*wy1*wx0);
        atom_add<L2LOCAL>(p+16513,   val*wz1*wy1*wx1);
        return;
    }
    if (x0 < -1 || x0 > 127 || y0 < -1 || y0 > 127 || z0 < -1 || z0 > 127)
        return;
#pragma unroll
    for (int dz = 0; dz < 2; ++dz) {
        int zi = z0 + dz;
        if ((unsigned)zi >= 128u) continue;
        float wz = dz ? fz : 1.f - fz;
#pragma unroll
        for (int dy = 0; dy < 2; ++dy) {
            int yi = y0 + dy;
            if ((unsigned)yi >= 128u) continue;
            float wy = dy ? fy : 1.f - fy;
#pragma unroll
            for (int dx = 0; dx < 2; ++dx) {
                int xi = x0 + dx;
                if ((unsigned)xi >= 128u) continue;
                float wx = dx ? fx : 1.f - fx;
                atom_add<L2LOCAL>(v + zi*16384 + yi*128 + xi, val*wz*wy*wx);
            }
        }
    }
}

// ---------------------------------------------------------------------------
// precompute shift[n][k] = R_n @ off_k + t_n + center  (48*45*3 floats)
__global__ void k_shifts(const float* __restrict__ trans, float* __restrict__ shifts)
{
    int i = blockIdx.x * blockDim.x + threadIdx.x;
    if (i >= NSL * NK) return;
    int n = i / NK, k = i % NK;
    int kz = k / 9, ky = (k % 9) / 3, kx = k % 3;
    float ox = (float)(kx - 1);
    float oy = (float)(ky - 1);
    float oz = (float)(kz - 2);
    const float* T = trans + n * 12;
    shifts[i*3+0] = T[0]*ox + T[1]*oy + T[2]*oz  + T[3]  + 63.5f;
    shifts[i*3+1] = T[4]*ox + T[5]*oy + T[6]*oz  + T[7]  + 63.5f;
    shifts[i*3+2] = T[8]*ox + T[9]*oy + T[10]*oz + T[11] + 63.5f;
}

// ---------------------------------------------------------------------------
// fused AtA: per pixel gather s = sum_k w_k * trilerp(p, pt_k) then splat w_k*s
// L2LOCAL: pout is 8 per-XCD copies; splat into copies[xcc_id] with L2 atomics.
template<bool L2LOCAL>
__global__ __launch_bounds__(256) void k_ata(const float* __restrict__ pin,
                                             float* __restrict__ pout,
                                             const float* __restrict__ shifts,
                                             const float* __restrict__ psf,
                                             const float* __restrict__ trans)
{
    __shared__ float sh[NK*4];            // [k*3+i] shifts, [135+k] weights
    int n   = blockIdx.x >> 6;
    int tid = threadIdx.x;
    if (tid < NK*3) sh[tid] = shifts[n*NK*3 + tid];
    if (tid >= 192 && tid < 192 + NK) sh[NK*3 + (tid - 192)] = psf[tid - 192];
    const float* T = trans + n * 12;
    float R00 = T[0], R01 = T[1], R10 = T[4], R11 = T[5], R20 = T[8], R21 = T[9];
    __syncthreads();

    float* pdst = L2LOCAL ? pout + (size_t)xcc_id() * NVOX : pout;

    int idx = (blockIdx.x & 63) * 256 + tid;
    int h = idx >> 7, w = idx & 127;
    float bx = ((float)w - 63.5f) * 1.25f;
    float by = ((float)h - 63.5f) * 1.25f;
    float rbx = R00*bx + R01*by;
    float rby = R10*bx + R11*by;
    float rbz = R20*bx + R21*by;

    float s = 0.f;
#pragma unroll 1
    for (int k = 0; k < NK; ++k)
        s += sh[NK*3+k] * trilerp_gather(pin, rbx + sh[k*3], rby + sh[k*3+1], rbz + sh[k*3+2]);

#pragma unroll 1
    for (int k = 0; k < NK; ++k)
        trilerp_splat<L2LOCAL>(pdst, rbx + sh[k*3], rby + sh[k*3+1], rbz + sh[k*3+2], sh[NK*3+k] * s);
}

// At only (for b = At(y))
template<bool L2LOCAL>
__global__ __launch_bounds__(256) void k_at(const float* __restrict__ y,
                                            float* __restrict__ pout,
                                            const float* __restrict__ shifts,
                                            const float* __restrict__ psf,
                                            const float* __restrict__ trans)
{
    __shared__ float sh[NK*4];
    int n   = blockIdx.x >> 6;
    int tid = threadIdx.x;
    if (tid < NK*3) sh[tid] = shifts[n*NK*3 + tid];
    if (tid >= 192 && tid < 192 + NK) sh[NK*3 + (tid - 192)] = psf[tid - 192];
    const float* T = trans + n * 12;
    float R00 = T[0], R01 = T[1], R10 = T[4], R11 = T[5], R20 = T[8], R21 = T[9];
    __syncthreads();

    float* pdst = L2LOCAL ? pout + (size_t)xcc_id() * NVOX : pout;

    int idx = (blockIdx.x & 63) * 256 + tid;
    int h = idx >> 7, w = idx & 127;
    float bx = ((float)w - 63.5f) * 1.25f;
    float by = ((float)h - 63.5f) * 1.25f;
    float rbx = R00*bx + R01*by;
    float rby = R10*bx + R11*by;
    float rbz = R20*bx + R21*by;

    float val = y[n * 16384 + idx];
#pragma unroll 1
    for (int k = 0; k < NK; ++k)
        trilerp_splat<L2LOCAL>(pdst, rbx + sh[k*3], rby + sh[k*3+1], rbz + sh[k*3+2], sh[NK*3+k] * val);
}

// sum the 8 per-XCD copies into dst (float4-vectorized)
__global__ __launch_bounds__(256) void k_reduce8(const float* __restrict__ copies,
                                                 float* __restrict__ dst)
{
    int i = blockIdx.x * blockDim.x + threadIdx.x;
    int stride = gridDim.x * blockDim.x;
    const float4* c = (const float4*)copies;
    float4* d = (float4*)dst;
    for (; i < NVOX/4; i += stride) {
        float4 s = c[i];
#pragma unroll
        for (int j = 1; j < 8; ++j) {
            float4 t = c[(size_t)j * (NVOX/4) + i];
            s.x += t.x; s.y += t.y; s.z += t.z; s.w += t.w;
        }
        d[i] = s;
    }
}

// ---------------------------------------------------------------------------
// reductions / CG vector updates
__device__ __forceinline__ void block_reduce_add(double s, double* out)
{
    for (int o = 32; o > 0; o >>= 1) s += __shfl_down(s, o);
    __shared__ double ls[4];
    int lane = threadIdx.x & 63, wid = threadIdx.x >> 6;
    if (lane == 0) ls[wid] = s;
    __syncthreads();
    if (threadIdx.x == 0) atomicAdd(out, ls[0] + ls[1] + ls[2] + ls[3]);
}

__global__ __launch_bounds__(256) void k_init(const float* __restrict__ b,
                                              const float* __restrict__ Ax,
                                              float* __restrict__ r,
                                              float* __restrict__ p,
                                              double* rr0)
{
    double s = 0.0;
    for (int i = blockIdx.x * blockDim.x + threadIdx.x; i < NVOX;
         i += gridDim.x * blockDim.x) {
        float rv = b[i] - Ax[i];
        r[i] = rv;
        p[i] = rv;
        s += (double)rv * (double)rv;
    }
    block_reduce_add(s, rr0);
}

__global__ __launch_bounds__(256) void k_dot(const float* __restrict__ a,
                                             const float* __restrict__ b,
                                             double* out)
{
    double s = 0.0;
    for (int i = blockIdx.x * blockDim.x + threadIdx.x; i < NVOX;
         i += gridDim.x * blockDim.x)
        s += (double)a[i] * (double)b[i];
    block_reduce_add(s, out);
}

__global__ __launch_bounds__(256) void k_update_xr(float* __restrict__ x,
                                                   float* __restrict__ r,
                                                   const float* __restrict__ p,
                                                   const float* __restrict__ Ap,
                                                   const double* rr, const double* pap,
                                                   double* rrn, int do_r)
{
    float alpha = (float)(rr[0] / pap[0]);
    double s = 0.0;
    for (int i = blockIdx.x * blockDim.x + threadIdx.x; i < NVOX;
         i += gridDim.x * blockDim.x) {
        x[i] += alpha * p[i];
        if (do_r) {
            float rn = r[i] - alpha * Ap[i];
            r[i] = rn;
            s += (double)rn * (double)rn;
        }
    }
    block_reduce_add(s, rrn);
}

__global__ __launch_bounds__(256) void k_update_p(float* __restrict__ p,
                                                  const float* __restrict__ r,
                                                  const double* rrn, const double* rro)
{
    float beta = (float)(rrn[0] / rro[0]);
    for (int i = blockIdx.x * blockDim.x + threadIdx.x; i < NVOX;
         i += gridDim.x * blockDim.x)
        p[i] = r[i] + beta * p[i];
}

__global__ __launch_bounds__(256) void k_relu(const float* __restrict__ x,
                                              float* __restrict__ out)
{
    for (int i = blockIdx.x * blockDim.x + threadIdx.x; i < NVOX;
         i += gridDim.x * blockDim.x)
        out[i] = fmaxf(x[i], 0.f);
}

// ---------------------------------------------------------------------------
extern "C" void kernel_launch(void* const* d_in, const int* in_sizes, int n_in,
                              void* d_out, int out_size, void* d_ws, size_t ws_size,
                              hipStream_t stream)
{
    const float* vol    = (const float*)d_in[0];   // 128^3
    const float* slices = (const float*)d_in[1];   // 48*128*128
    const float* trans  = (const float*)d_in[2];   // 48*3*4
    const float* psf    = (const float*)d_in[3];   // 45
    float* out = (float*)d_out;

    const size_t VB = (size_t)NVOX * 4;            // 8 MB
    char* w = (char*)d_ws;
    float* x      = (float*)(w);
    float* b      = (float*)(w + VB);
    float* r      = (float*)(w + VB*2);
    float* p      = (float*)(w + VB*3);
    float* Ap     = (float*)(w + VB*4);
    float* shifts = (float*)(w + VB*5);            // 25920 B
    double* sc    = (double*)(w + VB*5 + 32768);   // 21 doubles
    float* copies = (float*)(w + VB*6);            // 8 * 8 MB (fast path only)

    const bool fast = ws_size >= VB * 14;          // 112 MB

    hipMemsetAsync(sc, 0, 21 * sizeof(double), stream);
    hipLaunchKernelGGL(k_shifts, dim3(9), dim3(256), 0, stream, trans, shifts);

    // b = At(y)
    if (fast) {
        hipMemsetAsync(copies, 0, VB * 8, stream);
        hipLaunchKernelGGL(k_at<true>, dim3(NSL * 64), dim3(256), 0, stream,
                           slices, copies, shifts, psf, trans);
        hipLaunchKernelGGL(k_reduce8, dim3(2048), dim3(256), 0, stream, copies, b);
    } else {
        hipMemsetAsync(b, 0, VB, stream);
        hipLaunchKernelGGL(k_at<false>, dim3(NSL * 64), dim3(256), 0, stream,
                           slices, b, shifts, psf, trans);
    }

    // x = vol (initial guess)
    hipMemcpyAsync(x, vol, VB, hipMemcpyDeviceToDevice, stream);

    // Ax = AtA(x)
    if (fast) {
        hipMemsetAsync(copies, 0, VB * 8, stream);
        hipLaunchKernelGGL(k_ata<true>, dim3(NSL * 64), dim3(256), 0, stream,
                           x, copies, shifts, psf, trans);
        hipLaunchKernelGGL(k_reduce8, dim3(2048), dim3(256), 0, stream, copies, Ap);
    } else {
        hipMemsetAsync(Ap, 0, VB, stream);
        hipLaunchKernelGGL(k_ata<false>, dim3(NSL * 64), dim3(256), 0, stream,
                           x, Ap, shifts, psf, trans);
    }

    // r = b - Ax; p = r; rr0 = <r,r>
    hipLaunchKernelGGL(k_init, dim3(512), dim3(256), 0, stream, b, Ap, r, p, sc + 0);

    for (int i = 0; i < 10; ++i) {
        if (fast) {
            hipMemsetAsync(copies, 0, VB * 8, stream);
            hipLaunchKernelGGL(k_ata<true>, dim3(NSL * 64), dim3(256), 0, stream,
                               p, copies, shifts, psf, trans);
            hipLaunchKernelGGL(k_reduce8, dim3(2048), dim3(256), 0, stream, copies, Ap);
        } else {
            hipMemsetAsync(Ap, 0, VB, stream);
            hipLaunchKernelGGL(k_ata<false>, dim3(NSL * 64), dim3(256), 0, stream,
                               p, Ap, shifts, psf, trans);
        }
        hipLaunchKernelGGL(k_dot, dim3(512), dim3(256), 0, stream, p, Ap, sc + 11 + i);
        hipLaunchKernelGGL(k_update_xr, dim3(512), dim3(256), 0, stream,
                           x, r, p, Ap, sc + i, sc + 11 + i, sc + i + 1, (int)(i < 9));
        if (i < 9)
            hipLaunchKernelGGL(k_update_p, dim3(512), dim3(256), 0, stream,
                               p, r, sc + i + 1, sc + i);
    }

    hipLaunchKernelGGL(k_relu, dim3(512), dim3(256), 0, stream, x, out);
}

// Round 4
// 19260.309 us; speedup vs baseline: 1.8461x; 1.8461x over previous
//
#include <hip/hip_runtime.h>

#define NVOX (128*128*128)
#define NK 45
#define NSL 48
#define LDSF 12288   // per-block accumulation tile budget (floats) = 48 KB

// ---------------------------------------------------------------------------
// trilinear gather with reference semantics (out-of-bounds corners contribute 0)
__device__ __forceinline__ float trilerp_gather(const float* __restrict__ v,
                                                float x, float y, float z)
{
    float x0f = floorf(x), y0f = floorf(y), z0f = floorf(z);
    int x0 = (int)x0f, y0 = (int)y0f, z0 = (int)z0f;
    float fx = x - x0f, fy = y - y0f, fz = z - z0f;

    if (((unsigned)x0 < 127u) & ((unsigned)y0 < 127u) & ((unsigned)z0 < 127u)) {
        const float* p = v + z0*16384 + y0*128 + x0;
        float v000 = p[0],     v001 = p[1];
        float v010 = p[128],   v011 = p[129];
        float v100 = p[16384], v101 = p[16385];
        float v110 = p[16512], v111 = p[16513];
        float c00 = v000 + fx*(v001 - v000);
        float c01 = v010 + fx*(v011 - v010);
        float c10 = v100 + fx*(v101 - v100);
        float c11 = v110 + fx*(v111 - v110);
        float c0  = c00 + fy*(c01 - c00);
        float c1  = c10 + fy*(c11 - c10);
        return c0 + fz*(c1 - c0);
    }
    if (x0 < -1 || x0 > 127 || y0 < -1 || y0 > 127 || z0 < -1 || z0 > 127)
        return 0.f;
    float acc = 0.f;
#pragma unroll
    for (int dz = 0; dz < 2; ++dz) {
        int zi = z0 + dz;
        if ((unsigned)zi >= 128u) continue;
        float wz = dz ? fz : 1.f - fz;
#pragma unroll
        for (int dy = 0; dy < 2; ++dy) {
            int yi = y0 + dy;
            if ((unsigned)yi >= 128u) continue;
            float wy = dy ? fy : 1.f - fy;
#pragma unroll
            for (int dx = 0; dx < 2; ++dx) {
                int xi = x0 + dx;
                if ((unsigned)xi >= 128u) continue;
                float wx = dx ? fx : 1.f - fx;
                acc += wz*wy*wx * v[zi*16384 + yi*128 + xi];
            }
        }
    }
    return acc;
}

// direct global-atomic splat (fallback path only)
__device__ __forceinline__ void trilerp_splat_global(float* __restrict__ v,
                                                     float x, float y, float z, float val)
{
    float x0f = floorf(x), y0f = floorf(y), z0f = floorf(z);
    int x0 = (int)x0f, y0 = (int)y0f, z0 = (int)z0f;
    float fx = x - x0f, fy = y - y0f, fz = z - z0f;
    if (x0 < -1 || x0 > 127 || y0 < -1 || y0 > 127 || z0 < -1 || z0 > 127)
        return;
#pragma unroll
    for (int dz = 0; dz < 2; ++dz) {
        int zi = z0 + dz;
        if ((unsigned)zi >= 128u) continue;
        float wz = dz ? fz : 1.f - fz;
#pragma unroll
        for (int dy = 0; dy < 2; ++dy) {
            int yi = y0 + dy;
            if ((unsigned)yi >= 128u) continue;
            float wy = dy ? fy : 1.f - fy;
#pragma unroll
            for (int dx = 0; dx < 2; ++dx) {
                int xi = x0 + dx;
                if ((unsigned)xi >= 128u) continue;
                float wx = dx ? fx : 1.f - fx;
                unsafeAtomicAdd(v + zi*16384 + yi*128 + xi, val*wz*wy*wx);
            }
        }
    }
}

// LDS splat: AABB guarantees all 8 corners are inside the local tile.
__device__ __forceinline__ void trilerp_splat_lds(float* __restrict__ tile,
                                                  int x_lo, int y_lo, int z_lo,
                                                  int dx, int dxdy,
                                                  float x, float y, float z, float val)
{
    float x0f = floorf(x), y0f = floorf(y), z0f = floorf(z);
    int lx = (int)x0f - x_lo, ly = (int)y0f - y_lo, lz = (int)z0f - z_lo;
    float fx = x - x0f, fy = y - y0f, fz = z - z0f;
    float wx1 = fx, wx0 = 1.f - fx;
    float wy1 = fy, wy0 = 1.f - fy;
    float wz1 = fz, wz0 = 1.f - fz;
    float* p = tile + lz*dxdy + ly*dx + lx;
    atomicAdd(p,            val*wz0*wy0*wx0);
    atomicAdd(p+1,          val*wz0*wy0*wx1);
    atomicAdd(p+dx,         val*wz0*wy1*wx0);
    atomicAdd(p+dx+1,       val*wz0*wy1*wx1);
    atomicAdd(p+dxdy,       val*wz1*wy0*wx0);
    atomicAdd(p+dxdy+1,     val*wz1*wy0*wx1);
    atomicAdd(p+dxdy+dx,    val*wz1*wy1*wx0);
    atomicAdd(p+dxdy+dx+1,  val*wz1*wy1*wx1);
}

// ---------------------------------------------------------------------------
// precompute shift[n][k] = R_n @ off_k + t_n + center  (48*45*3 floats)
__global__ void k_shifts(const float* __restrict__ trans, float* __restrict__ shifts)
{
    int i = blockIdx.x * blockDim.x + threadIdx.x;
    if (i >= NSL * NK) return;
    int n = i / NK, k = i % NK;
    int kz = k / 9, ky = (k % 9) / 3, kx = k % 3;
    float ox = (float)(kx - 1);
    float oy = (float)(ky - 1);
    float oz = (float)(kz - 2);
    const float* T = trans + n * 12;
    shifts[i*3+0] = T[0]*ox + T[1]*oy + T[2]*oz  + T[3]  + 63.5f;
    shifts[i*3+1] = T[4]*ox + T[5]*oy + T[6]*oz  + T[7]  + 63.5f;
    shifts[i*3+2] = T[8]*ox + T[9]*oy + T[10]*oz + T[11] + 63.5f;
}

// ---------------------------------------------------------------------------
// projection kernel over 16x16 pixel tiles with LDS-privatized splat.
// GATHER=true : fused AtA  (val = sum_k w_k * trilerp(pin, pt_k), then splat w_k*val)
// GATHER=false: At only    (val = y[pixel])
template<bool GATHER>
__global__ __launch_bounds__(256) void k_proj(const float* __restrict__ pin,
                                              float* __restrict__ pout,
                                              const float* __restrict__ shifts,
                                              const float* __restrict__ psf,
                                              const float* __restrict__ trans)
{
    __shared__ float tile[LDSF];
    __shared__ float sh[NK*4];            // [k*3+i] shifts, [135+k] weights
    __shared__ int   box[8];              // x_lo,y_lo,z_lo,dx,dy,dz,total,fallback

    int n   = blockIdx.x >> 6;
    int t2  = blockIdx.x & 63;            // 8x8 tiles of 16x16 px
    int th  = t2 >> 3, tw = t2 & 7;
    int tid = threadIdx.x;

    if (tid < NK*3) sh[tid] = shifts[n*NK*3 + tid];
    if (tid >= 192 && tid < 192 + NK) sh[NK*3 + (tid - 192)] = psf[tid - 192];
    for (int i = tid; i < LDSF; i += 256) tile[i] = 0.f;
    const float* T = trans + n * 12;
    float R00 = T[0], R01 = T[1], R10 = T[4], R11 = T[5], R20 = T[8], R21 = T[9];
    __syncthreads();

    if (tid == 0) {
        float sxmn =  1e30f, sxmx = -1e30f;
        float symn =  1e30f, symx = -1e30f;
        float szmn =  1e30f, szmx = -1e30f;
        for (int k = 0; k < NK; ++k) {
            float sx = sh[k*3], sy = sh[k*3+1], sz = sh[k*3+2];
            sxmn = fminf(sxmn, sx); sxmx = fmaxf(sxmx, sx);
            symn = fminf(symn, sy); symx = fmaxf(symx, sy);
            szmn = fminf(szmn, sz); szmx = fmaxf(szmx, sz);
        }
        float cbx = ((float)(tw*16) + 7.5f - 63.5f) * 1.25f;
        float cby = ((float)(th*16) + 7.5f - 63.5f) * 1.25f;
        const float hs = 9.375f;  // 7.5 * 1.25
        float cx = R00*cbx + R01*cby, hx = (fabsf(R00) + fabsf(R01)) * hs;
        float cy = R10*cbx + R11*cby, hy = (fabsf(R10) + fabsf(R11)) * hs;
        float cz = R20*cbx + R21*cby, hz = (fabsf(R20) + fabsf(R21)) * hs;
        int x_lo = (int)floorf(cx - hx + sxmn), x_hi = (int)floorf(cx + hx + sxmx) + 1;
        int y_lo = (int)floorf(cy - hy + symn), y_hi = (int)floorf(cy + hy + symx) + 1;
        int z_lo = (int)floorf(cz - hz + szmn), z_hi = (int)floorf(cz + hz + szmx) + 1;
        int dx = x_hi - x_lo + 1, dy = y_hi - y_lo + 1, dz = z_hi - z_lo + 1;
        int total = dx * dy * dz;
        box[0] = x_lo; box[1] = y_lo; box[2] = z_lo;
        box[3] = dx;   box[4] = dy;   box[5] = dz;
        box[6] = total;
        box[7] = (total > LDSF) ? 1 : 0;
    }
    __syncthreads();

    int x_lo = box[0], y_lo = box[1], z_lo = box[2];
    int dx = box[3], dxdy = box[3] * box[4];
    int total = box[6], fallback = box[7];

    int ty = tid >> 4, tx = tid & 15;
    int h = th*16 + ty, w = tw*16 + tx;
    float bx = ((float)w - 63.5f) * 1.25f;
    float by = ((float)h - 63.5f) * 1.25f;
    float rbx = R00*bx + R01*by;
    float rby = R10*bx + R11*by;
    float rbz = R20*bx + R21*by;

    float val;
    if (GATHER) {
        float s = 0.f;
#pragma unroll 1
        for (int k = 0; k < NK; ++k)
            s += sh[NK*3+k] * trilerp_gather(pin, rbx + sh[k*3], rby + sh[k*3+1], rbz + sh[k*3+2]);
        val = s;
    } else {
        val = pin[n * 16384 + (h << 7) + w];
    }

    if (!fallback) {
#pragma unroll 1
        for (int k = 0; k < NK; ++k)
            trilerp_splat_lds(tile, x_lo, y_lo, z_lo, dx, dxdy,
                              rbx + sh[k*3], rby + sh[k*3+1], rbz + sh[k*3+2],
                              sh[NK*3+k] * val);
        __syncthreads();
        // flush nonzero, in-bounds cells
        for (int c = tid; c < total; c += 256) {
            float v = tile[c];
            if (v != 0.f) {
                int lz = c / dxdy;
                int rem = c - lz * dxdy;
                int ly = rem / dx;
                int lx = rem - ly * dx;
                int gx = x_lo + lx, gy = y_lo + ly, gz = z_lo + lz;
                if (((unsigned)gx < 128u) & ((unsigned)gy < 128u) & ((unsigned)gz < 128u))
                    unsafeAtomicAdd(pout + gz*16384 + gy*128 + gx, v);
            }
        }
    } else {
#pragma unroll 1
        for (int k = 0; k < NK; ++k)
            trilerp_splat_global(pout, rbx + sh[k*3], rby + sh[k*3+1], rbz + sh[k*3+2],
                                 sh[NK*3+k] * val);
    }
}

// ---------------------------------------------------------------------------
// reductions / CG vector updates
__device__ __forceinline__ void block_reduce_add(double s, double* out)
{
    for (int o = 32; o > 0; o >>= 1) s += __shfl_down(s, o);
    __shared__ double ls[4];
    int lane = threadIdx.x & 63, wid = threadIdx.x >> 6;
    if (lane == 0) ls[wid] = s;
    __syncthreads();
    if (threadIdx.x == 0) atomicAdd(out, ls[0] + ls[1] + ls[2] + ls[3]);
}

__global__ __launch_bounds__(256) void k_init(const float* __restrict__ b,
                                              const float* __restrict__ Ax,
                                              float* __restrict__ r,
                                              float* __restrict__ p,
                                              double* rr0)
{
    double s = 0.0;
    for (int i = blockIdx.x * blockDim.x + threadIdx.x; i < NVOX;
         i += gridDim.x * blockDim.x) {
        float rv = b[i] - Ax[i];
        r[i] = rv;
        p[i] = rv;
        s += (double)rv * (double)rv;
    }
    block_reduce_add(s, rr0);
}

__global__ __launch_bounds__(256) void k_dot(const float* __restrict__ a,
                                             const float* __restrict__ b,
                                             double* out)
{
    double s = 0.0;
    for (int i = blockIdx.x * blockDim.x + threadIdx.x; i < NVOX;
         i += gridDim.x * blockDim.x)
        s += (double)a[i] * (double)b[i];
    block_reduce_add(s, out);
}

__global__ __launch_bounds__(256) void k_update_xr(float* __restrict__ x,
                                                   float* __restrict__ r,
                                                   const float* __restrict__ p,
                                                   const float* __restrict__ Ap,
                                                   const double* rr, const double* pap,
                                                   double* rrn, int do_r)
{
    float alpha = (float)(rr[0] / pap[0]);
    double s = 0.0;
    for (int i = blockIdx.x * blockDim.x + threadIdx.x; i < NVOX;
         i += gridDim.x * blockDim.x) {
        x[i] += alpha * p[i];
        if (do_r) {
            float rn = r[i] - alpha * Ap[i];
            r[i] = rn;
            s += (double)rn * (double)rn;
        }
    }
    block_reduce_add(s, rrn);
}

__global__ __launch_bounds__(256) void k_update_p(float* __restrict__ p,
                                                  const float* __restrict__ r,
                                                  const double* rrn, const double* rro)
{
    float beta = (float)(rrn[0] / rro[0]);
    for (int i = blockIdx.x * blockDim.x + threadIdx.x; i < NVOX;
         i += gridDim.x * blockDim.x)
        p[i] = r[i] + beta * p[i];
}

__global__ __launch_bounds__(256) void k_relu(const float* __restrict__ x,
                                              float* __restrict__ out)
{
    for (int i = blockIdx.x * blockDim.x + threadIdx.x; i < NVOX;
         i += gridDim.x * blockDim.x)
        out[i] = fmaxf(x[i], 0.f);
}

// ---------------------------------------------------------------------------
extern "C" void kernel_launch(void* const* d_in, const int* in_sizes, int n_in,
                              void* d_out, int out_size, void* d_ws, size_t ws_size,
                              hipStream_t stream)
{
    const float* vol    = (const float*)d_in[0];   // 128^3
    const float* slices = (const float*)d_in[1];   // 48*128*128
    const float* trans  = (const float*)d_in[2];   // 48*3*4
    const float* psf    = (const float*)d_in[3];   // 45
    float* out = (float*)d_out;

    const size_t VB = (size_t)NVOX * 4;            // 8 MB
    char* w = (char*)d_ws;
    float* x      = (float*)(w);
    float* b      = (float*)(w + VB);
    float* r      = (float*)(w + VB*2);
    float* p      = (float*)(w + VB*3);
    float* Ap     = (float*)(w + VB*4);
    float* shifts = (float*)(w + VB*5);            // 25920 B
    double* sc    = (double*)(w + VB*5 + 32768);   // 21 doubles
    // sc[0..10] = rr_i, sc[11..20] = pAp_i

    hipMemsetAsync(sc, 0, 21 * sizeof(double), stream);
    hipLaunchKernelGGL(k_shifts, dim3(9), dim3(256), 0, stream, trans, shifts);

    // b = At(y)
    hipMemsetAsync(b, 0, VB, stream);
    hipLaunchKernelGGL(k_proj<false>, dim3(NSL * 64), dim3(256), 0, stream,
                       slices, b, shifts, psf, trans);

    // x = vol (initial guess)
    hipMemcpyAsync(x, vol, VB, hipMemcpyDeviceToDevice, stream);

    // Ax = AtA(x)
    hipMemsetAsync(Ap, 0, VB, stream);
    hipLaunchKernelGGL(k_proj<true>, dim3(NSL * 64), dim3(256), 0, stream,
                       x, Ap, shifts, psf, trans);

    // r = b - Ax; p = r; rr0 = <r,r>
    hipLaunchKernelGGL(k_init, dim3(512), dim3(256), 0, stream, b, Ap, r, p, sc + 0);

    for (int i = 0; i < 10; ++i) {
        hipMemsetAsync(Ap, 0, VB, stream);
        hipLaunchKernelGGL(k_proj<true>, dim3(NSL * 64), dim3(256), 0, stream,
                           p, Ap, shifts, psf, trans);
        hipLaunchKernelGGL(k_dot, dim3(512), dim3(256), 0, stream, p, Ap, sc + 11 + i);
        hipLaunchKernelGGL(k_update_xr, dim3(512), dim3(256), 0, stream,
                           x, r, p, Ap, sc + i, sc + 11 + i, sc + i + 1, (int)(i < 9));
        if (i < 9)
            hipLaunchKernelGGL(k_update_p, dim3(512), dim3(256), 0, stream,
                               p, r, sc + i + 1, sc + i);
    }

    hipLaunchKernelGGL(k_relu, dim3(512), dim3(256), 0, stream, x, out);
}

// Round 5
// 18280.350 us; speedup vs baseline: 1.9451x; 1.0536x over previous
//
#include <hip/hip_runtime.h>

#define NVOX (128*128*128)
#define NK 45
#define NSL 48
#define LDSF 12288   // per-block slab/accum tile budget (floats) = 48 KB

// ---------------------------------------------------------------------------
// global-memory trilerp gather (fallback path only)
__device__ __forceinline__ float trilerp_gather_g(const float* __restrict__ v,
                                                  float x, float y, float z)
{
    float x0f = floorf(x), y0f = floorf(y), z0f = floorf(z);
    int x0 = (int)x0f, y0 = (int)y0f, z0 = (int)z0f;
    float fx = x - x0f, fy = y - y0f, fz = z - z0f;
    if (x0 < -1 || x0 > 127 || y0 < -1 || y0 > 127 || z0 < -1 || z0 > 127)
        return 0.f;
    float acc = 0.f;
#pragma unroll
    for (int dz = 0; dz < 2; ++dz) {
        int zi = z0 + dz;
        if ((unsigned)zi >= 128u) continue;
        float wz = dz ? fz : 1.f - fz;
#pragma unroll
        for (int dy = 0; dy < 2; ++dy) {
            int yi = y0 + dy;
            if ((unsigned)yi >= 128u) continue;
            float wy = dy ? fy : 1.f - fy;
#pragma unroll
            for (int dx = 0; dx < 2; ++dx) {
                int xi = x0 + dx;
                if ((unsigned)xi >= 128u) continue;
                float wx = dx ? fx : 1.f - fx;
                acc += wz*wy*wx * v[zi*16384 + yi*128 + xi];
            }
        }
    }
    return acc;
}

// global-atomic splat (fallback path only)
__device__ __forceinline__ void trilerp_splat_g(float* __restrict__ v,
                                                float x, float y, float z, float val)
{
    float x0f = floorf(x), y0f = floorf(y), z0f = floorf(z);
    int x0 = (int)x0f, y0 = (int)y0f, z0 = (int)z0f;
    float fx = x - x0f, fy = y - y0f, fz = z - z0f;
    if (x0 < -1 || x0 > 127 || y0 < -1 || y0 > 127 || z0 < -1 || z0 > 127)
        return;
#pragma unroll
    for (int dz = 0; dz < 2; ++dz) {
        int zi = z0 + dz;
        if ((unsigned)zi >= 128u) continue;
        float wz = dz ? fz : 1.f - fz;
#pragma unroll
        for (int dy = 0; dy < 2; ++dy) {
            int yi = y0 + dy;
            if ((unsigned)yi >= 128u) continue;
            float wy = dy ? fy : 1.f - fy;
#pragma unroll
            for (int dx = 0; dx < 2; ++dx) {
                int xi = x0 + dx;
                if ((unsigned)xi >= 128u) continue;
                float wx = dx ? fx : 1.f - fx;
                unsafeAtomicAdd(v + zi*16384 + yi*128 + xi, val*wz*wy*wx);
            }
        }
    }
}

// LDS gather: slab covers all 8 corners; outside-volume cells hold 0.
__device__ __forceinline__ float trilerp_gather_lds(const float* __restrict__ tile,
                                                    int x_lo, int y_lo, int z_lo,
                                                    int dx, int dxdy,
                                                    float x, float y, float z)
{
    float x0f = floorf(x), y0f = floorf(y), z0f = floorf(z);
    int lx = (int)x0f - x_lo, ly = (int)y0f - y_lo, lz = (int)z0f - z_lo;
    float fx = x - x0f, fy = y - y0f, fz = z - z0f;
    const float* p = tile + lz*dxdy + ly*dx + lx;
    float v000 = p[0],       v001 = p[1];
    float v010 = p[dx],      v011 = p[dx+1];
    float v100 = p[dxdy],    v101 = p[dxdy+1];
    float v110 = p[dxdy+dx], v111 = p[dxdy+dx+1];
    float c00 = v000 + fx*(v001 - v000);
    float c01 = v010 + fx*(v011 - v010);
    float c10 = v100 + fx*(v101 - v100);
    float c11 = v110 + fx*(v111 - v110);
    float c0  = c00 + fy*(c01 - c00);
    float c1  = c10 + fy*(c11 - c10);
    return c0 + fz*(c1 - c0);
}

// LDS splat: AABB guarantees all 8 corners are inside the local tile.
__device__ __forceinline__ void trilerp_splat_lds(float* __restrict__ tile,
                                                  int x_lo, int y_lo, int z_lo,
                                                  int dx, int dxdy,
                                                  float x, float y, float z, float val)
{
    float x0f = floorf(x), y0f = floorf(y), z0f = floorf(z);
    int lx = (int)x0f - x_lo, ly = (int)y0f - y_lo, lz = (int)z0f - z_lo;
    float fx = x - x0f, fy = y - y0f, fz = z - z0f;
    float wx1 = fx, wx0 = 1.f - fx;
    float wy1 = fy, wy0 = 1.f - fy;
    float wz1 = fz, wz0 = 1.f - fz;
    float* p = tile + lz*dxdy + ly*dx + lx;
    atomicAdd(p,            val*wz0*wy0*wx0);
    atomicAdd(p+1,          val*wz0*wy0*wx1);
    atomicAdd(p+dx,         val*wz0*wy1*wx0);
    atomicAdd(p+dx+1,       val*wz0*wy1*wx1);
    atomicAdd(p+dxdy,       val*wz1*wy0*wx0);
    atomicAdd(p+dxdy+1,     val*wz1*wy0*wx1);
    atomicAdd(p+dxdy+dx,    val*wz1*wy1*wx0);
    atomicAdd(p+dxdy+dx+1,  val*wz1*wy1*wx1);
}

// ---------------------------------------------------------------------------
// precompute shift[n][k] = R_n @ off_k + t_n + center  (48*45*3 floats)
__global__ void k_shifts(const float* __restrict__ trans, float* __restrict__ shifts)
{
    int i = blockIdx.x * blockDim.x + threadIdx.x;
    if (i >= NSL * NK) return;
    int n = i / NK, k = i % NK;
    int kz = k / 9, ky = (k % 9) / 3, kx = k % 3;
    float ox = (float)(kx - 1);
    float oy = (float)(ky - 1);
    float oz = (float)(kz - 2);
    const float* T = trans + n * 12;
    shifts[i*3+0] = T[0]*ox + T[1]*oy + T[2]*oz  + T[3]  + 63.5f;
    shifts[i*3+1] = T[4]*ox + T[5]*oy + T[6]*oz  + T[7]  + 63.5f;
    shifts[i*3+2] = T[8]*ox + T[9]*oy + T[10]*oz + T[11] + 63.5f;
}

// ---------------------------------------------------------------------------
// projection kernel over 16x16 pixel tiles. LDS slab is used BOTH as the
// gather source (staged copy of pin over the tile's AABB) and, after a
// barrier + re-zero, as the splat accumulator.
// GATHER=true : fused AtA  (val = sum_k w_k * trilerp(pin, pt_k), then splat w_k*val)
// GATHER=false: At only    (val = y[pixel])
template<bool GATHER>
__global__ __launch_bounds__(256) void k_proj(const float* __restrict__ pin,
                                              float* __restrict__ pout,
                                              const float* __restrict__ shifts,
                                              const float* __restrict__ psf,
                                              const float* __restrict__ trans)
{
    __shared__ float tile[LDSF];
    __shared__ float sh[NK*4];            // [k*3+i] shifts, [135+k] weights
    __shared__ int   box[8];              // x_lo,y_lo,z_lo,dx,dy,dz,total,fallback

    int n   = blockIdx.x >> 6;
    int t2  = blockIdx.x & 63;            // 8x8 tiles of 16x16 px
    int th  = t2 >> 3, tw = t2 & 7;
    int tid = threadIdx.x;

    if (tid < NK*3) sh[tid] = shifts[n*NK*3 + tid];
    if (tid >= 192 && tid < 192 + NK) sh[NK*3 + (tid - 192)] = psf[tid - 192];
    const float* T = trans + n * 12;
    float R00 = T[0], R01 = T[1], R10 = T[4], R11 = T[5], R20 = T[8], R21 = T[9];
    __syncthreads();

    if (tid == 0) {
        float sxmn =  1e30f, sxmx = -1e30f;
        float symn =  1e30f, symx = -1e30f;
        float szmn =  1e30f, szmx = -1e30f;
        for (int k = 0; k < NK; ++k) {
            float sx = sh[k*3], sy = sh[k*3+1], sz = sh[k*3+2];
            sxmn = fminf(sxmn, sx); sxmx = fmaxf(sxmx, sx);
            symn = fminf(symn, sy); symx = fmaxf(symx, sy);
            szmn = fminf(szmn, sz); szmx = fmaxf(szmx, sz);
        }
        float cbx = ((float)(tw*16) + 7.5f - 63.5f) * 1.25f;
        float cby = ((float)(th*16) + 7.5f - 63.5f) * 1.25f;
        const float hs = 9.375f;  // 7.5 * 1.25
        float cx = R00*cbx + R01*cby, hx = (fabsf(R00) + fabsf(R01)) * hs;
        float cy = R10*cbx + R11*cby, hy = (fabsf(R10) + fabsf(R11)) * hs;
        float cz = R20*cbx + R21*cby, hz = (fabsf(R20) + fabsf(R21)) * hs;
        int x_lo = (int)floorf(cx - hx + sxmn), x_hi = (int)floorf(cx + hx + sxmx) + 1;
        int y_lo = (int)floorf(cy - hy + symn), y_hi = (int)floorf(cy + hy + symx) + 1;
        int z_lo = (int)floorf(cz - hz + szmn), z_hi = (int)floorf(cz + hz + szmx) + 1;
        int dx = x_hi - x_lo + 1, dy = y_hi - y_lo + 1, dz = z_hi - z_lo + 1;
        int total = dx * dy * dz;
        box[0] = x_lo; box[1] = y_lo; box[2] = z_lo;
        box[3] = dx;   box[4] = dy;   box[5] = dz;
        box[6] = total;
        box[7] = (total > LDSF) ? 1 : 0;
    }
    __syncthreads();

    int x_lo = box[0], y_lo = box[1], z_lo = box[2];
    int dx = box[3], dxdy = box[3] * box[4];
    int total = box[6], fallback = box[7];

    int ty = tid >> 4, tx = tid & 15;
    int h = th*16 + ty, w = tw*16 + tx;
    float bx = ((float)w - 63.5f) * 1.25f;
    float by = ((float)h - 63.5f) * 1.25f;
    float rbx = R00*bx + R01*by;
    float rby = R10*bx + R11*by;
    float rbz = R20*bx + R21*by;

    if (!fallback) {
        float val;
        if (GATHER) {
            // stage slab of pin into LDS (0 outside the volume)
            for (int c = tid; c < total; c += 256) {
                int lz = c / dxdy;
                int rem = c - lz * dxdy;
                int ly = rem / dx;
                int lx = rem - ly * dx;
                int gx = x_lo + lx, gy = y_lo + ly, gz = z_lo + lz;
                float v = 0.f;
                if (((unsigned)gx < 128u) & ((unsigned)gy < 128u) & ((unsigned)gz < 128u))
                    v = pin[gz*16384 + gy*128 + gx];
                tile[c] = v;
            }
            __syncthreads();
            float s = 0.f;
#pragma unroll 1
            for (int k = 0; k < NK; ++k)
                s += sh[NK*3+k] * trilerp_gather_lds(tile, x_lo, y_lo, z_lo, dx, dxdy,
                                                     rbx + sh[k*3], rby + sh[k*3+1],
                                                     rbz + sh[k*3+2]);
            val = s;
            __syncthreads();          // everyone done reading slab
        } else {
            val = pin[n * 16384 + (h << 7) + w];
        }

        // zero accumulator region
        for (int c = tid; c < total; c += 256) tile[c] = 0.f;
        __syncthreads();

#pragma unroll 1
        for (int k = 0; k < NK; ++k)
            trilerp_splat_lds(tile, x_lo, y_lo, z_lo, dx, dxdy,
                              rbx + sh[k*3], rby + sh[k*3+1], rbz + sh[k*3+2],
                              sh[NK*3+k] * val);
        __syncthreads();

        // flush nonzero, in-bounds cells
        for (int c = tid; c < total; c += 256) {
            float v = tile[c];
            if (v != 0.f) {
                int lz = c / dxdy;
                int rem = c - lz * dxdy;
                int ly = rem / dx;
                int lx = rem - ly * dx;
                int gx = x_lo + lx, gy = y_lo + ly, gz = z_lo + lz;
                if (((unsigned)gx < 128u) & ((unsigned)gy < 128u) & ((unsigned)gz < 128u))
                    unsafeAtomicAdd(pout + gz*16384 + gy*128 + gx, v);
            }
        }
    } else {
        float val;
        if (GATHER) {
            float s = 0.f;
#pragma unroll 1
            for (int k = 0; k < NK; ++k)
                s += sh[NK*3+k] * trilerp_gather_g(pin, rbx + sh[k*3], rby + sh[k*3+1],
                                                   rbz + sh[k*3+2]);
            val = s;
        } else {
            val = pin[n * 16384 + (h << 7) + w];
        }
#pragma unroll 1
        for (int k = 0; k < NK; ++k)
            trilerp_splat_g(pout, rbx + sh[k*3], rby + sh[k*3+1], rbz + sh[k*3+2],
                            sh[NK*3+k] * val);
    }
}

// ---------------------------------------------------------------------------
// reductions / CG vector updates
__device__ __forceinline__ void block_reduce_add(double s, double* out)
{
    for (int o = 32; o > 0; o >>= 1) s += __shfl_down(s, o);
    __shared__ double ls[4];
    int lane = threadIdx.x & 63, wid = threadIdx.x >> 6;
    if (lane == 0) ls[wid] = s;
    __syncthreads();
    if (threadIdx.x == 0) atomicAdd(out, ls[0] + ls[1] + ls[2] + ls[3]);
}

__global__ __launch_bounds__(256) void k_init(const float* __restrict__ b,
                                              const float* __restrict__ Ax,
                                              float* __restrict__ r,
                                              float* __restrict__ p,
                                              double* rr0)
{
    double s = 0.0;
    for (int i = blockIdx.x * blockDim.x + threadIdx.x; i < NVOX;
         i += gridDim.x * blockDim.x) {
        float rv = b[i] - Ax[i];
        r[i] = rv;
        p[i] = rv;
        s += (double)rv * (double)rv;
    }
    block_reduce_add(s, rr0);
}

__global__ __launch_bounds__(256) void k_dot(const float* __restrict__ a,
                                             const float* __restrict__ b,
                                             double* out)
{
    double s = 0.0;
    for (int i = blockIdx.x * blockDim.x + threadIdx.x; i < NVOX;
         i += gridDim.x * blockDim.x)
        s += (double)a[i] * (double)b[i];
    block_reduce_add(s, out);
}

__global__ __launch_bounds__(256) void k_update_xr(float* __restrict__ x,
                                                   float* __restrict__ r,
                                                   const float* __restrict__ p,
                                                   const float* __restrict__ Ap,
                                                   const double* rr, const double* pap,
                                                   double* rrn, int do_r)
{
    float alpha = (float)(rr[0] / pap[0]);
    double s = 0.0;
    for (int i = blockIdx.x * blockDim.x + threadIdx.x; i < NVOX;
         i += gridDim.x * blockDim.x) {
        x[i] += alpha * p[i];
        if (do_r) {
            float rn = r[i] - alpha * Ap[i];
            r[i] = rn;
            s += (double)rn * (double)rn;
        }
    }
    block_reduce_add(s, rrn);
}

__global__ __launch_bounds__(256) void k_update_p(float* __restrict__ p,
                                                  const float* __restrict__ r,
                                                  const double* rrn, const double* rro)
{
    float beta = (float)(rrn[0] / rro[0]);
    for (int i = blockIdx.x * blockDim.x + threadIdx.x; i < NVOX;
         i += gridDim.x * blockDim.x)
        p[i] = r[i] + beta * p[i];
}

__global__ __launch_bounds__(256) void k_relu(const float* __restrict__ x,
                                              float* __restrict__ out)
{
    for (int i = blockIdx.x * blockDim.x + threadIdx.x; i < NVOX;
         i += gridDim.x * blockDim.x)
        out[i] = fmaxf(x[i], 0.f);
}

// ---------------------------------------------------------------------------
extern "C" void kernel_launch(void* const* d_in, const int* in_sizes, int n_in,
                              void* d_out, int out_size, void* d_ws, size_t ws_size,
                              hipStream_t stream)
{
    const float* vol    = (const float*)d_in[0];   // 128^3
    const float* slices = (const float*)d_in[1];   // 48*128*128
    const float* trans  = (const float*)d_in[2];   // 48*3*4
    const float* psf    = (const float*)d_in[3];   // 45
    float* out = (float*)d_out;

    const size_t VB = (size_t)NVOX * 4;            // 8 MB
    char* w = (char*)d_ws;
    float* x      = (float*)(w);
    float* b      = (float*)(w + VB);
    float* r      = (float*)(w + VB*2);
    float* p      = (float*)(w + VB*3);
    float* Ap     = (float*)(w + VB*4);
    float* shifts = (float*)(w + VB*5);            // 25920 B
    double* sc    = (double*)(w + VB*5 + 32768);   // 21 doubles
    // sc[0..10] = rr_i, sc[11..20] = pAp_i

    hipMemsetAsync(sc, 0, 21 * sizeof(double), stream);
    hipLaunchKernelGGL(k_shifts, dim3(9), dim3(256), 0, stream, trans, shifts);

    // b = At(y)
    hipMemsetAsync(b, 0, VB, stream);
    hipLaunchKernelGGL(k_proj<false>, dim3(NSL * 64), dim3(256), 0, stream,
                       slices, b, shifts, psf, trans);

    // x = vol (initial guess)
    hipMemcpyAsync(x, vol, VB, hipMemcpyDeviceToDevice, stream);

    // Ax = AtA(x)
    hipMemsetAsync(Ap, 0, VB, stream);
    hipLaunchKernelGGL(k_proj<true>, dim3(NSL * 64), dim3(256), 0, stream,
                       x, Ap, shifts, psf, trans);

    // r = b - Ax; p = r; rr0 = <r,r>
    hipLaunchKernelGGL(k_init, dim3(512), dim3(256), 0, stream, b, Ap, r, p, sc + 0);

    for (int i = 0; i < 10; ++i) {
        hipMemsetAsync(Ap, 0, VB, stream);
        hipLaunchKernelGGL(k_proj<true>, dim3(NSL * 64), dim3(256), 0, stream,
                           p, Ap, shifts, psf, trans);
        hipLaunchKernelGGL(k_dot, dim3(512), dim3(256), 0, stream, p, Ap, sc + 11 + i);
        hipLaunchKernelGGL(k_update_xr, dim3(512), dim3(256), 0, stream,
                           x, r, p, Ap, sc + i, sc + 11 + i, sc + i + 1, (int)(i < 9));
        if (i < 9)
            hipLaunchKernelGGL(k_update_p, dim3(512), dim3(256), 0, stream,
                               p, r, sc + i + 1, sc + i);
    }

    hipLaunchKernelGGL(k_relu, dim3(512), dim3(256), 0, stream, x, out);
}

// Round 6
// 18247.539 us; speedup vs baseline: 1.9486x; 1.0018x over previous
//
#include <hip/hip_runtime.h>

#define NVOX (128*128*128)
#define NK 45
#define NSL 48
#define LDSF 12288   // per-block slab/accum tile budget (floats) = 48 KB
#define NT 512       // threads per block (2 tap-groups x 256 pixels)

// ---------------------------------------------------------------------------
// global-memory trilerp gather (fallback path only)
__device__ __forceinline__ float trilerp_gather_g(const float* __restrict__ v,
                                                  float x, float y, float z)
{
    float x0f = floorf(x), y0f = floorf(y), z0f = floorf(z);
    int x0 = (int)x0f, y0 = (int)y0f, z0 = (int)z0f;
    float fx = x - x0f, fy = y - y0f, fz = z - z0f;
    if (x0 < -1 || x0 > 127 || y0 < -1 || y0 > 127 || z0 < -1 || z0 > 127)
        return 0.f;
    float acc = 0.f;
#pragma unroll
    for (int dz = 0; dz < 2; ++dz) {
        int zi = z0 + dz;
        if ((unsigned)zi >= 128u) continue;
        float wz = dz ? fz : 1.f - fz;
#pragma unroll
        for (int dy = 0; dy < 2; ++dy) {
            int yi = y0 + dy;
            if ((unsigned)yi >= 128u) continue;
            float wy = dy ? fy : 1.f - fy;
#pragma unroll
            for (int dx = 0; dx < 2; ++dx) {
                int xi = x0 + dx;
                if ((unsigned)xi >= 128u) continue;
                float wx = dx ? fx : 1.f - fx;
                acc += wz*wy*wx * v[zi*16384 + yi*128 + xi];
            }
        }
    }
    return acc;
}

// global-atomic splat (fallback path only)
__device__ __forceinline__ void trilerp_splat_g(float* __restrict__ v,
                                                float x, float y, float z, float val)
{
    float x0f = floorf(x), y0f = floorf(y), z0f = floorf(z);
    int x0 = (int)x0f, y0 = (int)y0f, z0 = (int)z0f;
    float fx = x - x0f, fy = y - y0f, fz = z - z0f;
    if (x0 < -1 || x0 > 127 || y0 < -1 || y0 > 127 || z0 < -1 || z0 > 127)
        return;
#pragma unroll
    for (int dz = 0; dz < 2; ++dz) {
        int zi = z0 + dz;
        if ((unsigned)zi >= 128u) continue;
        float wz = dz ? fz : 1.f - fz;
#pragma unroll
        for (int dy = 0; dy < 2; ++dy) {
            int yi = y0 + dy;
            if ((unsigned)yi >= 128u) continue;
            float wy = dy ? fy : 1.f - fy;
#pragma unroll
            for (int dx = 0; dx < 2; ++dx) {
                int xi = x0 + dx;
                if ((unsigned)xi >= 128u) continue;
                float wx = dx ? fx : 1.f - fx;
                unsafeAtomicAdd(v + zi*16384 + yi*128 + xi, val*wz*wy*wx);
            }
        }
    }
}

// LDS gather: slab covers all 8 corners; outside-volume cells hold 0.
__device__ __forceinline__ float trilerp_gather_lds(const float* __restrict__ tile,
                                                    int x_lo, int y_lo, int z_lo,
                                                    int dx, int dxdy,
                                                    float x, float y, float z)
{
    float x0f = floorf(x), y0f = floorf(y), z0f = floorf(z);
    int lx = (int)x0f - x_lo, ly = (int)y0f - y_lo, lz = (int)z0f - z_lo;
    float fx = x - x0f, fy = y - y0f, fz = z - z0f;
    const float* p = tile + lz*dxdy + ly*dx + lx;
    float v000 = p[0],       v001 = p[1];
    float v010 = p[dx],      v011 = p[dx+1];
    float v100 = p[dxdy],    v101 = p[dxdy+1];
    float v110 = p[dxdy+dx], v111 = p[dxdy+dx+1];
    float c00 = v000 + fx*(v001 - v000);
    float c01 = v010 + fx*(v011 - v010);
    float c10 = v100 + fx*(v101 - v100);
    float c11 = v110 + fx*(v111 - v110);
    float c0  = c00 + fy*(c01 - c00);
    float c1  = c10 + fy*(c11 - c10);
    return c0 + fz*(c1 - c0);
}

// LDS splat: AABB guarantees all 8 corners are inside the local tile.
__device__ __forceinline__ void trilerp_splat_lds(float* __restrict__ tile,
                                                  int x_lo, int y_lo, int z_lo,
                                                  int dx, int dxdy,
                                                  float x, float y, float z, float val)
{
    float x0f = floorf(x), y0f = floorf(y), z0f = floorf(z);
    int lx = (int)x0f - x_lo, ly = (int)y0f - y_lo, lz = (int)z0f - z_lo;
    float fx = x - x0f, fy = y - y0f, fz = z - z0f;
    float wx1 = fx, wx0 = 1.f - fx;
    float wy1 = fy, wy0 = 1.f - fy;
    float wz1 = fz, wz0 = 1.f - fz;
    float* p = tile + lz*dxdy + ly*dx + lx;
    atomicAdd(p,            val*wz0*wy0*wx0);
    atomicAdd(p+1,          val*wz0*wy0*wx1);
    atomicAdd(p+dx,         val*wz0*wy1*wx0);
    atomicAdd(p+dx+1,       val*wz0*wy1*wx1);
    atomicAdd(p+dxdy,       val*wz1*wy0*wx0);
    atomicAdd(p+dxdy+1,     val*wz1*wy0*wx1);
    atomicAdd(p+dxdy+dx,    val*wz1*wy1*wx0);
    atomicAdd(p+dxdy+dx+1,  val*wz1*wy1*wx1);
}

// ---------------------------------------------------------------------------
// precompute shift[n][k] = R_n @ off_k + t_n + center  (48*45*3 floats)
__global__ void k_shifts(const float* __restrict__ trans, float* __restrict__ shifts)
{
    int i = blockIdx.x * blockDim.x + threadIdx.x;
    if (i >= NSL * NK) return;
    int n = i / NK, k = i % NK;
    int kz = k / 9, ky = (k % 9) / 3, kx = k % 3;
    float ox = (float)(kx - 1);
    float oy = (float)(ky - 1);
    float oz = (float)(kz - 2);
    const float* T = trans + n * 12;
    shifts[i*3+0] = T[0]*ox + T[1]*oy + T[2]*oz  + T[3]  + 63.5f;
    shifts[i*3+1] = T[4]*ox + T[5]*oy + T[6]*oz  + T[7]  + 63.5f;
    shifts[i*3+2] = T[8]*ox + T[9]*oy + T[10]*oz + T[11] + 63.5f;
}

// ---------------------------------------------------------------------------
// projection kernel over 16x16 pixel tiles, 512 threads: thread = (half, px).
// half 0 handles taps [0,23), half 1 taps [23,45). LDS slab is the gather
// source then (after re-zero) the splat accumulator.
template<bool GATHER>
__global__ __launch_bounds__(NT, 6) void k_proj(const float* __restrict__ pin,
                                                float* __restrict__ pout,
                                                const float* __restrict__ shifts,
                                                const float* __restrict__ psf,
                                                const float* __restrict__ trans)
{
    __shared__ float tile[LDSF];
    __shared__ float sh[NK*4];            // [k*3+i] shifts, [135+k] weights
    __shared__ float part[NT];            // per-(half,px) partial gather sums
    __shared__ int   box[8];              // x_lo,y_lo,z_lo,dx,dy,dz,total,fallback

    int n   = blockIdx.x >> 6;
    int t2  = blockIdx.x & 63;            // 8x8 tiles of 16x16 px
    int th  = t2 >> 3, tw = t2 & 7;
    int tid = threadIdx.x;
    int px  = tid & 255;
    int half = tid >> 8;
    int k_beg = half ? 23 : 0;
    int k_end = half ? NK : 23;

    if (tid < NK*3) sh[tid] = shifts[n*NK*3 + tid];
    if (tid >= 192 && tid < 192 + NK) sh[NK*3 + (tid - 192)] = psf[tid - 192];
    const float* T = trans + n * 12;
    float R00 = T[0], R01 = T[1], R10 = T[4], R11 = T[5], R20 = T[8], R21 = T[9];
    __syncthreads();

    if (tid == 0) {
        float sxmn =  1e30f, sxmx = -1e30f;
        float symn =  1e30f, symx = -1e30f;
        float szmn =  1e30f, szmx = -1e30f;
        for (int k = 0; k < NK; ++k) {
            float sx = sh[k*3], sy = sh[k*3+1], sz = sh[k*3+2];
            sxmn = fminf(sxmn, sx); sxmx = fmaxf(sxmx, sx);
            symn = fminf(symn, sy); symx = fmaxf(symx, sy);
            szmn = fminf(szmn, sz); szmx = fmaxf(szmx, sz);
        }
        float cbx = ((float)(tw*16) + 7.5f - 63.5f) * 1.25f;
        float cby = ((float)(th*16) + 7.5f - 63.5f) * 1.25f;
        const float hs = 9.375f;  // 7.5 * 1.25
        float cx = R00*cbx + R01*cby, hx = (fabsf(R00) + fabsf(R01)) * hs;
        float cy = R10*cbx + R11*cby, hy = (fabsf(R10) + fabsf(R11)) * hs;
        float cz = R20*cbx + R21*cby, hz = (fabsf(R20) + fabsf(R21)) * hs;
        int x_lo = (int)floorf(cx - hx + sxmn), x_hi = (int)floorf(cx + hx + sxmx) + 1;
        int y_lo = (int)floorf(cy - hy + symn), y_hi = (int)floorf(cy + hy + symx) + 1;
        int z_lo = (int)floorf(cz - hz + szmn), z_hi = (int)floorf(cz + hz + szmx) + 1;
        int dx = x_hi - x_lo + 1, dy = y_hi - y_lo + 1, dz = z_hi - z_lo + 1;
        int total = dx * dy * dz;
        box[0] = x_lo; box[1] = y_lo; box[2] = z_lo;
        box[3] = dx;   box[4] = dy;   box[5] = dz;
        box[6] = total;
        box[7] = (total > LDSF) ? 1 : 0;
    }
    __syncthreads();

    int x_lo = box[0], y_lo = box[1], z_lo = box[2];
    int dx = box[3], dxdy = box[3] * box[4];
    int total = box[6], fallback = box[7];

    int ty = px >> 4, tx = px & 15;
    int h = th*16 + ty, w = tw*16 + tx;
    float bx = ((float)w - 63.5f) * 1.25f;
    float by = ((float)h - 63.5f) * 1.25f;
    float rbx = R00*bx + R01*by;
    float rby = R10*bx + R11*by;
    float rbz = R20*bx + R21*by;

    if (!fallback) {
        float val;
        if (GATHER) {
            // stage slab of pin into LDS (0 outside the volume)
            for (int c = tid; c < total; c += NT) {
                int lz = c / dxdy;
                int rem = c - lz * dxdy;
                int ly = rem / dx;
                int lx = rem - ly * dx;
                int gx = x_lo + lx, gy = y_lo + ly, gz = z_lo + lz;
                float v = 0.f;
                if (((unsigned)gx < 128u) & ((unsigned)gy < 128u) & ((unsigned)gz < 128u))
                    v = pin[gz*16384 + gy*128 + gx];
                tile[c] = v;
            }
            __syncthreads();
            float s = 0.f;
#pragma unroll 1
            for (int k = k_beg; k < k_end; ++k)
                s += sh[NK*3+k] * trilerp_gather_lds(tile, x_lo, y_lo, z_lo, dx, dxdy,
                                                     rbx + sh[k*3], rby + sh[k*3+1],
                                                     rbz + sh[k*3+2]);
            part[tid] = s;
            __syncthreads();          // partials written AND slab reads done
            val = part[px] + part[px + 256];
        } else {
            val = pin[n * 16384 + (h << 7) + w];
        }

        // zero accumulator region
        for (int c = tid; c < total; c += NT) tile[c] = 0.f;
        __syncthreads();

#pragma unroll 1
        for (int k = k_beg; k < k_end; ++k)
            trilerp_splat_lds(tile, x_lo, y_lo, z_lo, dx, dxdy,
                              rbx + sh[k*3], rby + sh[k*3+1], rbz + sh[k*3+2],
                              sh[NK*3+k] * val);
        __syncthreads();

        // flush nonzero, in-bounds cells
        for (int c = tid; c < total; c += NT) {
            float v = tile[c];
            if (v != 0.f) {
                int lz = c / dxdy;
                int rem = c - lz * dxdy;
                int ly = rem / dx;
                int lx = rem - ly * dx;
                int gx = x_lo + lx, gy = y_lo + ly, gz = z_lo + lz;
                if (((unsigned)gx < 128u) & ((unsigned)gy < 128u) & ((unsigned)gz < 128u))
                    unsafeAtomicAdd(pout + gz*16384 + gy*128 + gx, v);
            }
        }
    } else {
        float val;
        if (GATHER) {
            float s = 0.f;
#pragma unroll 1
            for (int k = k_beg; k < k_end; ++k)
                s += sh[NK*3+k] * trilerp_gather_g(pin, rbx + sh[k*3], rby + sh[k*3+1],
                                                   rbz + sh[k*3+2]);
            part[tid] = s;
            __syncthreads();
            val = part[px] + part[px + 256];
        } else {
            val = pin[n * 16384 + (h << 7) + w];
        }
#pragma unroll 1
        for (int k = k_beg; k < k_end; ++k)
            trilerp_splat_g(pout, rbx + sh[k*3], rby + sh[k*3+1], rbz + sh[k*3+2],
                            sh[NK*3+k] * val);
    }
}

// ---------------------------------------------------------------------------
// reductions / CG vector updates
__device__ __forceinline__ void block_reduce_add(double s, double* out)
{
    for (int o = 32; o > 0; o >>= 1) s += __shfl_down(s, o);
    __shared__ double ls[4];
    int lane = threadIdx.x & 63, wid = threadIdx.x >> 6;
    if (lane == 0) ls[wid] = s;
    __syncthreads();
    if (threadIdx.x == 0) atomicAdd(out, ls[0] + ls[1] + ls[2] + ls[3]);
}

__global__ __launch_bounds__(256) void k_init(const float* __restrict__ b,
                                              const float* __restrict__ Ax,
                                              float* __restrict__ r,
                                              float* __restrict__ p,
                                              double* rr0)
{
    double s = 0.0;
    for (int i = blockIdx.x * blockDim.x + threadIdx.x; i < NVOX;
         i += gridDim.x * blockDim.x) {
        float rv = b[i] - Ax[i];
        r[i] = rv;
        p[i] = rv;
        s += (double)rv * (double)rv;
    }
    block_reduce_add(s, rr0);
}

__global__ __launch_bounds__(256) void k_dot(const float* __restrict__ a,
                                             const float* __restrict__ b,
                                             double* out)
{
    double s = 0.0;
    for (int i = blockIdx.x * blockDim.x + threadIdx.x; i < NVOX;
         i += gridDim.x * blockDim.x)
        s += (double)a[i] * (double)b[i];
    block_reduce_add(s, out);
}

__global__ __launch_bounds__(256) void k_update_xr(float* __restrict__ x,
                                                   float* __restrict__ r,
                                                   const float* __restrict__ p,
                                                   const float* __restrict__ Ap,
                                                   const double* rr, const double* pap,
                                                   double* rrn, int do_r)
{
    float alpha = (float)(rr[0] / pap[0]);
    double s = 0.0;
    for (int i = blockIdx.x * blockDim.x + threadIdx.x; i < NVOX;
         i += gridDim.x * blockDim.x) {
        x[i] += alpha * p[i];
        if (do_r) {
            float rn = r[i] - alpha * Ap[i];
            r[i] = rn;
            s += (double)rn * (double)rn;
        }
    }
    block_reduce_add(s, rrn);
}

__global__ __launch_bounds__(256) void k_update_p(float* __restrict__ p,
                                                  const float* __restrict__ r,
                                                  const double* rrn, const double* rro)
{
    float beta = (float)(rrn[0] / rro[0]);
    for (int i = blockIdx.x * blockDim.x + threadIdx.x; i < NVOX;
         i += gridDim.x * blockDim.x)
        p[i] = r[i] + beta * p[i];
}

__global__ __launch_bounds__(256) void k_relu(const float* __restrict__ x,
                                              float* __restrict__ out)
{
    for (int i = blockIdx.x * blockDim.x + threadIdx.x; i < NVOX;
         i += gridDim.x * blockDim.x)
        out[i] = fmaxf(x[i], 0.f);
}

// ---------------------------------------------------------------------------
extern "C" void kernel_launch(void* const* d_in, const int* in_sizes, int n_in,
                              void* d_out, int out_size, void* d_ws, size_t ws_size,
                              hipStream_t stream)
{
    const float* vol    = (const float*)d_in[0];   // 128^3
    const float* slices = (const float*)d_in[1];   // 48*128*128
    const float* trans  = (const float*)d_in[2];   // 48*3*4
    const float* psf    = (const float*)d_in[3];   // 45
    float* out = (float*)d_out;

    const size_t VB = (size_t)NVOX * 4;            // 8 MB
    char* w = (char*)d_ws;
    float* x      = (float*)(w);
    float* b      = (float*)(w + VB);
    float* r      = (float*)(w + VB*2);
    float* p      = (float*)(w + VB*3);
    float* Ap     = (float*)(w + VB*4);
    float* shifts = (float*)(w + VB*5);            // 25920 B
    double* sc    = (double*)(w + VB*5 + 32768);   // 21 doubles
    // sc[0..10] = rr_i, sc[11..20] = pAp_i

    hipMemsetAsync(sc, 0, 21 * sizeof(double), stream);
    hipLaunchKernelGGL(k_shifts, dim3(9), dim3(256), 0, stream, trans, shifts);

    // b = At(y)
    hipMemsetAsync(b, 0, VB, stream);
    hipLaunchKernelGGL(k_proj<false>, dim3(NSL * 64), dim3(NT), 0, stream,
                       slices, b, shifts, psf, trans);

    // x = vol (initial guess)
    hipMemcpyAsync(x, vol, VB, hipMemcpyDeviceToDevice, stream);

    // Ax = AtA(x)
    hipMemsetAsync(Ap, 0, VB, stream);
    hipLaunchKernelGGL(k_proj<true>, dim3(NSL * 64), dim3(NT), 0, stream,
                       x, Ap, shifts, psf, trans);

    // r = b - Ax; p = r; rr0 = <r,r>
    hipLaunchKernelGGL(k_init, dim3(512), dim3(256), 0, stream, b, Ap, r, p, sc + 0);

    for (int i = 0; i < 10; ++i) {
        hipMemsetAsync(Ap, 0, VB, stream);
        hipLaunchKernelGGL(k_proj<true>, dim3(NSL * 64), dim3(NT), 0, stream,
                           p, Ap, shifts, psf, trans);
        hipLaunchKernelGGL(k_dot, dim3(512), dim3(256), 0, stream, p, Ap, sc + 11 + i);
        hipLaunchKernelGGL(k_update_xr, dim3(512), dim3(256), 0, stream,
                           x, r, p, Ap, sc + i, sc + 11 + i, sc + i + 1, (int)(i < 9));
        if (i < 9)
            hipLaunchKernelGGL(k_update_p, dim3(512), dim3(256), 0, stream,
                               p, r, sc + i + 1, sc + i);
    }

    hipLaunchKernelGGL(k_relu, dim3(512), dim3(256), 0, stream, x, out);
}

// Round 8
// 5417.112 us; speedup vs baseline: 6.5638x; 3.3685x over previous
//
#include <hip/hip_runtime.h>

#define NVOX (128*128*128)
#define NK 45
#define NSL 48
#define LDSF 12288   // splat tile budget (floats) = 48 KB

// ---------------------------------------------------------------------------
// global-memory trilerp gather (reference semantics: OOB corners contribute 0)
__device__ __forceinline__ float trilerp_gather_g(const float* __restrict__ v,
                                                  float x, float y, float z)
{
    float x0f = floorf(x), y0f = floorf(y), z0f = floorf(z);
    int x0 = (int)x0f, y0 = (int)y0f, z0 = (int)z0f;
    float fx = x - x0f, fy = y - y0f, fz = z - z0f;

    if (((unsigned)x0 < 127u) & ((unsigned)y0 < 127u) & ((unsigned)z0 < 127u)) {
        const float* p = v + z0*16384 + y0*128 + x0;
        float v000 = p[0],     v001 = p[1];
        float v010 = p[128],   v011 = p[129];
        float v100 = p[16384], v101 = p[16385];
        float v110 = p[16512], v111 = p[16513];
        float c00 = v000 + fx*(v001 - v000);
        float c01 = v010 + fx*(v011 - v010);
        float c10 = v100 + fx*(v101 - v100);
        float c11 = v110 + fx*(v111 - v110);
        float c0  = c00 + fy*(c01 - c00);
        float c1  = c10 + fy*(c11 - c10);
        return c0 + fz*(c1 - c0);
    }
    if (x0 < -1 || x0 > 127 || y0 < -1 || y0 > 127 || z0 < -1 || z0 > 127)
        return 0.f;
    float acc = 0.f;
#pragma unroll
    for (int dz = 0; dz < 2; ++dz) {
        int zi = z0 + dz;
        if ((unsigned)zi >= 128u) continue;
        float wz = dz ? fz : 1.f - fz;
#pragma unroll
        for (int dy = 0; dy < 2; ++dy) {
            int yi = y0 + dy;
            if ((unsigned)yi >= 128u) continue;
            float wy = dy ? fy : 1.f - fy;
#pragma unroll
            for (int dx = 0; dx < 2; ++dx) {
                int xi = x0 + dx;
                if ((unsigned)xi >= 128u) continue;
                float wx = dx ? fx : 1.f - fx;
                acc += wz*wy*wx * v[zi*16384 + yi*128 + xi];
            }
        }
    }
    return acc;
}

// global-atomic splat (oversize-AABB fallback only)
__device__ __forceinline__ void trilerp_splat_g(float* __restrict__ v,
                                                float x, float y, float z, float val)
{
    float x0f = floorf(x), y0f = floorf(y), z0f = floorf(z);
    int x0 = (int)x0f, y0 = (int)y0f, z0 = (int)z0f;
    float fx = x - x0f, fy = y - y0f, fz = z - z0f;
    if (x0 < -1 || x0 > 127 || y0 < -1 || y0 > 127 || z0 < -1 || z0 > 127)
        return;
#pragma unroll
    for (int dz = 0; dz < 2; ++dz) {
        int zi = z0 + dz;
        if ((unsigned)zi >= 128u) continue;
        float wz = dz ? fz : 1.f - fz;
#pragma unroll
        for (int dy = 0; dy < 2; ++dy) {
            int yi = y0 + dy;
            if ((unsigned)yi >= 128u) continue;
            float wy = dy ? fy : 1.f - fy;
#pragma unroll
            for (int dx = 0; dx < 2; ++dx) {
                int xi = x0 + dx;
                if ((unsigned)xi >= 128u) continue;
                float wx = dx ? fx : 1.f - fx;
                unsafeAtomicAdd(v + zi*16384 + yi*128 + xi, val*wz*wy*wx);
            }
        }
    }
}

// ---------------------------------------------------------------------------
// precompute shift[n][k] = R_n @ off_k + t_n + center  (48*45*3 floats)
__global__ void k_shifts(const float* __restrict__ trans, float* __restrict__ shifts)
{
    int i = blockIdx.x * blockDim.x + threadIdx.x;
    if (i >= NSL * NK) return;
    int n = i / NK, k = i % NK;
    int kz = k / 9, ky = (k % 9) / 3, kx = k % 3;
    float ox = (float)(kx - 1);
    float oy = (float)(ky - 1);
    float oz = (float)(kz - 2);
    const float* T = trans + n * 12;
    shifts[i*3+0] = T[0]*ox + T[1]*oy + T[2]*oz  + T[3]  + 63.5f;
    shifts[i*3+1] = T[4]*ox + T[5]*oy + T[6]*oz  + T[7]  + 63.5f;
    shifts[i*3+2] = T[8]*ox + T[9]*oy + T[10]*oz + T[11] + 63.5f;
}

// ---------------------------------------------------------------------------
// A-side: val[n,h,w] = sum_k w_k * trilerp(vol, R*base + shift_k)
__global__ __launch_bounds__(256) void k_gather(const float* __restrict__ vol,
                                                const float* __restrict__ shifts,
                                                const float* __restrict__ psf,
                                                const float* __restrict__ trans,
                                                float* __restrict__ val)
{
    __shared__ float sh[NK*4];
    int n = blockIdx.x >> 6, seg = blockIdx.x & 63, tid = threadIdx.x;
    for (int i = tid; i < NK*3; i += 256) sh[i] = shifts[n*NK*3 + i];
    if (tid < NK) sh[NK*3+tid] = psf[tid];
    const float* T = trans + n*12;
    float R00=T[0],R01=T[1],R10=T[4],R11=T[5],R20=T[8],R21=T[9];
    __syncthreads();

    int idx = seg*256 + tid;
    int h = idx >> 7, w = idx & 127;
    float bx = ((float)w - 63.5f)*1.25f;
    float by = ((float)h - 63.5f)*1.25f;
    float rbx = R00*bx + R01*by;
    float rby = R10*bx + R11*by;
    float rbz = R20*bx + R21*by;

    float s = 0.f;
#pragma unroll 3
    for (int k = 0; k < NK; ++k)
        s += sh[NK*3+k] * trilerp_gather_g(vol, rbx + sh[k*3], rby + sh[k*3+1],
                                           rbz + sh[k*3+2]);
    val[n*16384 + idx] = s;
}

// ---------------------------------------------------------------------------
// At-side: one WAVE per 16x16 tile, LDS slab accumulator.
// Race-free non-atomic RMW via 4 checkerboard parity phases: within a phase,
// active pixels differ by EVEN pixel steps, so projected base corners differ
// by >=2 voxels in x or y (|dX| >= 2.5*(R00-|R01|) >= 2, |dY| >= 2.5*(R11-|R10|))
// => the 2x2x2 corner boxes of any two lanes are disjoint. Between phases a
// full lgkmcnt(0) drain makes cross-lane LDS RAW safe. If the transform were
// too oblique for the proof, fall back to ds_add atomics (uniform branch).
__global__ __launch_bounds__(64) void k_splat(const float* __restrict__ val,
                                              float* __restrict__ pout,
                                              const float* __restrict__ shifts,
                                              const float* __restrict__ psf,
                                              const float* __restrict__ trans)
{
    __shared__ float tile[LDSF];
    __shared__ float sh[NK*4];
    int n = blockIdx.x >> 6, t2 = blockIdx.x & 63;
    int th = t2 >> 3, tw = t2 & 7;
    int lane = threadIdx.x;

    for (int i = lane; i < NK*3; i += 64) sh[i] = shifts[n*NK*3 + i];
    if (lane < NK) sh[NK*3+lane] = psf[lane];
    const float* T = trans + n*12;
    float R00=T[0],R01=T[1],R10=T[4],R11=T[5],R20=T[8],R21=T[9];
    __syncthreads();

    // AABB: lane-parallel min/max over the 45 tap shifts
    float sx0, sy0, sz0;
    if (lane < NK) { sx0 = sh[lane*3]; sy0 = sh[lane*3+1]; sz0 = sh[lane*3+2]; }
    else           { sx0 = sh[0];      sy0 = sh[1];        sz0 = sh[2]; }
    float sxmn=sx0,sxmx=sx0,symn=sy0,symx=sy0,szmn=sz0,szmx=sz0;
    for (int o = 32; o; o >>= 1) {
        sxmn = fminf(sxmn, __shfl_xor(sxmn,o)); sxmx = fmaxf(sxmx, __shfl_xor(sxmx,o));
        symn = fminf(symn, __shfl_xor(symn,o)); symx = fmaxf(symx, __shfl_xor(symx,o));
        szmn = fminf(szmn, __shfl_xor(szmn,o)); szmx = fmaxf(szmx, __shfl_xor(szmx,o));
    }
    float cbx = ((float)(tw*16) + 7.5f - 63.5f)*1.25f;
    float cby = ((float)(th*16) + 7.5f - 63.5f)*1.25f;
    const float hs = 9.375f;   // 7.5 * 1.25
    float cx = R00*cbx + R01*cby, hx = (fabsf(R00)+fabsf(R01))*hs;
    float cy = R10*cbx + R11*cby, hy = (fabsf(R10)+fabsf(R11))*hs;
    float cz = R20*cbx + R21*cby, hz = (fabsf(R20)+fabsf(R21))*hs;
    int x_lo = (int)floorf(cx-hx+sxmn), x_hi = (int)floorf(cx+hx+sxmx)+1;
    int y_lo = (int)floorf(cy-hy+symn), y_hi = (int)floorf(cy+hy+symx)+1;
    int z_lo = (int)floorf(cz-hz+szmn), z_hi = (int)floorf(cz+hz+szmx)+1;
    int dxs  = x_hi - x_lo + 1;
    int dys  = y_hi - y_lo + 1;
    int dzs  = z_hi - z_lo + 1;
    int dxdy = dxs * dys;
    int total = dxdy * dzs;

    bool safe = (2.5f*(R00 - fabsf(R01)) >= 2.0f) &&
                (2.5f*(R11 - fabsf(R10)) >= 2.0f);

    if (total <= LDSF) {
        for (int c = lane; c < total; c += 64) tile[c] = 0.f;
        __syncthreads();

        // per-phase pixel geometry (fully unrolled -> registers)
        float prbx[4], prby[4], prbz[4], pval[4];
#pragma unroll
        for (int p = 0; p < 4; ++p) {
            int w = tw*16 + 2*(lane & 7)  + (p & 1);
            int h = th*16 + 2*(lane >> 3) + (p >> 1);
            float bx = ((float)w - 63.5f)*1.25f;
            float by = ((float)h - 63.5f)*1.25f;
            prbx[p] = R00*bx + R01*by;
            prby[p] = R10*bx + R11*by;
            prbz[p] = R20*bx + R21*by;
            pval[p] = val[n*16384 + (h<<7) + w];
        }

#pragma unroll 1
        for (int k = 0; k < NK; ++k) {
            float sx = sh[k*3], sy = sh[k*3+1], sz = sh[k*3+2], wk = sh[NK*3+k];
#pragma unroll
            for (int p = 0; p < 4; ++p) {
                // drain all prior LDS ops: cross-lane RAW between phases/taps
                asm volatile("s_waitcnt lgkmcnt(0)" ::: "memory");
                float x = prbx[p] + sx, y = prby[p] + sy, z = prbz[p] + sz;
                float x0f = floorf(x), y0f = floorf(y), z0f = floorf(z);
                int lx = (int)x0f - x_lo, ly = (int)y0f - y_lo, lz = (int)z0f - z_lo;
                float fx = x - x0f, fy = y - y0f, fz = z - z0f;
                float vw = pval[p] * wk;
                float wx1 = fx, wx0 = 1.f - fx;
                float wy1 = fy, wy0 = 1.f - fy;
                float wz1 = fz, wz0 = 1.f - fz;
                float* q = tile + lz*dxdy + ly*dxs + lx;
                if (safe) {
                    q[0]          += vw*wz0*wy0*wx0;
                    q[1]          += vw*wz0*wy0*wx1;
                    q[dxs]        += vw*wz0*wy1*wx0;
                    q[dxs+1]      += vw*wz0*wy1*wx1;
                    q[dxdy]       += vw*wz1*wy0*wx0;
                    q[dxdy+1]     += vw*wz1*wy0*wx1;
                    q[dxdy+dxs]   += vw*wz1*wy1*wx0;
                    q[dxdy+dxs+1] += vw*wz1*wy1*wx1;
                } else {
                    atomicAdd(q,            vw*wz0*wy0*wx0);
                    atomicAdd(q+1,          vw*wz0*wy0*wx1);
                    atomicAdd(q+dxs,        vw*wz0*wy1*wx0);
                    atomicAdd(q+dxs+1,      vw*wz0*wy1*wx1);
                    atomicAdd(q+dxdy,       vw*wz1*wy0*wx0);
                    atomicAdd(q+dxdy+1,     vw*wz1*wy0*wx1);
                    atomicAdd(q+dxdy+dxs,   vw*wz1*wy1*wx0);
                    atomicAdd(q+dxdy+dxs+1, vw*wz1*wy1*wx1);
                }
            }
        }
        __syncthreads();

        for (int c = lane; c < total; c += 64) {
            float v2 = tile[c];
            if (v2 != 0.f) {
                int lz = c / dxdy;
                int rem = c - lz*dxdy;
                int ly = rem / dxs;
                int lx = rem - ly*dxs;
                int gx = x_lo+lx, gy = y_lo+ly, gz = z_lo+lz;
                if (((unsigned)gx < 128u) & ((unsigned)gy < 128u) & ((unsigned)gz < 128u))
                    unsafeAtomicAdd(pout + gz*16384 + gy*128 + gx, v2);
            }
        }
    } else {
        // fallback: direct global-atomic splat
        for (int s2 = 0; s2 < 4; ++s2) {
            int px = s2*64 + lane;
            int ty = px >> 4, tx = px & 15;
            int h = th*16 + ty, w = tw*16 + tx;
            float bx = ((float)w - 63.5f)*1.25f;
            float by = ((float)h - 63.5f)*1.25f;
            float rbx = R00*bx + R01*by;
            float rby = R10*bx + R11*by;
            float rbz = R20*bx + R21*by;
            float v = val[n*16384 + (h<<7) + w];
#pragma unroll 1
            for (int k = 0; k < NK; ++k)
                trilerp_splat_g(pout, rbx + sh[k*3], rby + sh[k*3+1],
                                rbz + sh[k*3+2], sh[NK*3+k] * v);
        }
    }
}

// ---------------------------------------------------------------------------
// reductions / CG vector updates
__device__ __forceinline__ void block_reduce_add(double s, double* out)
{
    for (int o = 32; o > 0; o >>= 1) s += __shfl_down(s, o);
    __shared__ double ls[4];
    int lane = threadIdx.x & 63, wid = threadIdx.x >> 6;
    if (lane == 0) ls[wid] = s;
    __syncthreads();
    if (threadIdx.x == 0) atomicAdd(out, ls[0] + ls[1] + ls[2] + ls[3]);
}

__global__ __launch_bounds__(256) void k_init(const float* __restrict__ b,
                                              const float* __restrict__ Ax,
                                              float* __restrict__ r,
                                              float* __restrict__ p,
                                              double* rr0)
{
    double s = 0.0;
    for (int i = blockIdx.x * blockDim.x + threadIdx.x; i < NVOX;
         i += gridDim.x * blockDim.x) {
        float rv = b[i] - Ax[i];
        r[i] = rv;
        p[i] = rv;
        s += (double)rv * (double)rv;
    }
    block_reduce_add(s, rr0);
}

__global__ __launch_bounds__(256) void k_dot(const float* __restrict__ a,
                                             const float* __restrict__ b,
                                             double* out)
{
    double s = 0.0;
    for (int i = blockIdx.x * blockDim.x + threadIdx.x; i < NVOX;
         i += gridDim.x * blockDim.x)
        s += (double)a[i] * (double)b[i];
    block_reduce_add(s, out);
}

__global__ __launch_bounds__(256) void k_update_xr(float* __restrict__ x,
                                                   float* __restrict__ r,
                                                   const float* __restrict__ p,
                                                   const float* __restrict__ Ap,
                                                   const double* rr, const double* pap,
                                                   double* rrn, int do_r)
{
    float alpha = (float)(rr[0] / pap[0]);
    double s = 0.0;
    for (int i = blockIdx.x * blockDim.x + threadIdx.x; i < NVOX;
         i += gridDim.x * blockDim.x) {
        x[i] += alpha * p[i];
        if (do_r) {
            float rn = r[i] - alpha * Ap[i];
            r[i] = rn;
            s += (double)rn * (double)rn;
        }
    }
    block_reduce_add(s, rrn);
}

__global__ __launch_bounds__(256) void k_update_p(float* __restrict__ p,
                                                  const float* __restrict__ r,
                                                  const double* rrn, const double* rro)
{
    float beta = (float)(rrn[0] / rro[0]);
    for (int i = blockIdx.x * blockDim.x + threadIdx.x; i < NVOX;
         i += gridDim.x * blockDim.x)
        p[i] = r[i] + beta * p[i];
}

__global__ __launch_bounds__(256) void k_relu(const float* __restrict__ x,
                                              float* __restrict__ out)
{
    for (int i = blockIdx.x * blockDim.x + threadIdx.x; i < NVOX;
         i += gridDim.x * blockDim.x)
        out[i] = fmaxf(x[i], 0.f);
}

// ---------------------------------------------------------------------------
extern "C" void kernel_launch(void* const* d_in, const int* in_sizes, int n_in,
                              void* d_out, int out_size, void* d_ws, size_t ws_size,
                              hipStream_t stream)
{
    const float* vol    = (const float*)d_in[0];   // 128^3
    const float* slices = (const float*)d_in[1];   // 48*128*128
    const float* trans  = (const float*)d_in[2];   // 48*3*4
    const float* psf    = (const float*)d_in[3];   // 45
    float* out = (float*)d_out;

    const size_t VB = (size_t)NVOX * 4;            // 8 MB
    char* w = (char*)d_ws;
    float* x      = (float*)(w);
    float* b      = (float*)(w + VB);
    float* r      = (float*)(w + VB*2);
    float* p      = (float*)(w + VB*3);
    float* Ap     = (float*)(w + VB*4);
    float* shifts = (float*)(w + VB*5);            // 25920 B
    double* sc    = (double*)(w + VB*5 + 32768);   // 21 doubles
    float* val    = (float*)(w + VB*6);            // 48*16384 floats = 3 MB

    hipMemsetAsync(sc, 0, 21 * sizeof(double), stream);
    hipLaunchKernelGGL(k_shifts, dim3(9), dim3(256), 0, stream, trans, shifts);

    // b = At(y): slices already have the val layout — splat directly
    hipMemsetAsync(b, 0, VB, stream);
    hipLaunchKernelGGL(k_splat, dim3(NSL * 64), dim3(64), 0, stream,
                       slices, b, shifts, psf, trans);

    // x = vol (initial guess)
    hipMemcpyAsync(x, vol, VB, hipMemcpyDeviceToDevice, stream);

    // Ax = AtA(x)
    hipMemsetAsync(Ap, 0, VB, stream);
    hipLaunchKernelGGL(k_gather, dim3(NSL * 64), dim3(256), 0, stream,
                       x, shifts, psf, trans, val);
    hipLaunchKernelGGL(k_splat, dim3(NSL * 64), dim3(64), 0, stream,
                       val, Ap, shifts, psf, trans);

    // r = b - Ax; p = r; rr0 = <r,r>
    hipLaunchKernelGGL(k_init, dim3(512), dim3(256), 0, stream, b, Ap, r, p, sc + 0);

    for (int i = 0; i < 10; ++i) {
        hipMemsetAsync(Ap, 0, VB, stream);
        hipLaunchKernelGGL(k_gather, dim3(NSL * 64), dim3(256), 0, stream,
                           p, shifts, psf, trans, val);
        hipLaunchKernelGGL(k_splat, dim3(NSL * 64), dim3(64), 0, stream,
                           val, Ap, shifts, psf, trans);
        hipLaunchKernelGGL(k_dot, dim3(512), dim3(256), 0, stream, p, Ap, sc + 11 + i);
        hipLaunchKernelGGL(k_update_xr, dim3(512), dim3(256), 0, stream,
                           x, r, p, Ap, sc + i, sc + 11 + i, sc + i + 1, (int)(i < 9));
        if (i < 9)
            hipLaunchKernelGGL(k_update_p, dim3(512), dim3(256), 0, stream,
                               p, r, sc + i + 1, sc + i);
    }

    hipLaunchKernelGGL(k_relu, dim3(512), dim3(256), 0, stream, x, out);
}

// Round 9
// 5351.559 us; speedup vs baseline: 6.6442x; 1.0122x over previous
//
#include <hip/hip_runtime.h>

#define NVOX (128*128*128)
#define NK 45
#define NSL 48
#define LDSF 12288   // splat tile budget (floats) = 48 KB

// ---------------------------------------------------------------------------
// global-memory trilerp gather (reference semantics: OOB corners contribute 0)
__device__ __forceinline__ float trilerp_gather_g(const float* __restrict__ v,
                                                  float x, float y, float z)
{
    float x0f = floorf(x), y0f = floorf(y), z0f = floorf(z);
    int x0 = (int)x0f, y0 = (int)y0f, z0 = (int)z0f;
    float fx = x - x0f, fy = y - y0f, fz = z - z0f;

    if (((unsigned)x0 < 127u) & ((unsigned)y0 < 127u) & ((unsigned)z0 < 127u)) {
        const float* p = v + z0*16384 + y0*128 + x0;
        float v000 = p[0],     v001 = p[1];
        float v010 = p[128],   v011 = p[129];
        float v100 = p[16384], v101 = p[16385];
        float v110 = p[16512], v111 = p[16513];
        float c00 = v000 + fx*(v001 - v000);
        float c01 = v010 + fx*(v011 - v010);
        float c10 = v100 + fx*(v101 - v100);
        float c11 = v110 + fx*(v111 - v110);
        float c0  = c00 + fy*(c01 - c00);
        float c1  = c10 + fy*(c11 - c10);
        return c0 + fz*(c1 - c0);
    }
    if (x0 < -1 || x0 > 127 || y0 < -1 || y0 > 127 || z0 < -1 || z0 > 127)
        return 0.f;
    float acc = 0.f;
#pragma unroll
    for (int dz = 0; dz < 2; ++dz) {
        int zi = z0 + dz;
        if ((unsigned)zi >= 128u) continue;
        float wz = dz ? fz : 1.f - fz;
#pragma unroll
        for (int dy = 0; dy < 2; ++dy) {
            int yi = y0 + dy;
            if ((unsigned)yi >= 128u) continue;
            float wy = dy ? fy : 1.f - fy;
#pragma unroll
            for (int dx = 0; dx < 2; ++dx) {
                int xi = x0 + dx;
                if ((unsigned)xi >= 128u) continue;
                float wx = dx ? fx : 1.f - fx;
                acc += wz*wy*wx * v[zi*16384 + yi*128 + xi];
            }
        }
    }
    return acc;
}

// global-atomic splat (oversize-AABB fallback only)
__device__ __forceinline__ void trilerp_splat_g(float* __restrict__ v,
                                                float x, float y, float z, float val)
{
    float x0f = floorf(x), y0f = floorf(y), z0f = floorf(z);
    int x0 = (int)x0f, y0 = (int)y0f, z0 = (int)z0f;
    float fx = x - x0f, fy = y - y0f, fz = z - z0f;
    if (x0 < -1 || x0 > 127 || y0 < -1 || y0 > 127 || z0 < -1 || z0 > 127)
        return;
#pragma unroll
    for (int dz = 0; dz < 2; ++dz) {
        int zi = z0 + dz;
        if ((unsigned)zi >= 128u) continue;
        float wz = dz ? fz : 1.f - fz;
#pragma unroll
        for (int dy = 0; dy < 2; ++dy) {
            int yi = y0 + dy;
            if ((unsigned)yi >= 128u) continue;
            float wy = dy ? fy : 1.f - fy;
#pragma unroll
            for (int dx = 0; dx < 2; ++dx) {
                int xi = x0 + dx;
                if ((unsigned)xi >= 128u) continue;
                float wx = dx ? fx : 1.f - fx;
                unsafeAtomicAdd(v + zi*16384 + yi*128 + xi, val*wz*wy*wx);
            }
        }
    }
}

// ---------------------------------------------------------------------------
// precompute shift[n][k] = R_n @ off_k + t_n + center  (48*45*3 floats)
__global__ void k_shifts(const float* __restrict__ trans, float* __restrict__ shifts)
{
    int i = blockIdx.x * blockDim.x + threadIdx.x;
    if (i >= NSL * NK) return;
    int n = i / NK, k = i % NK;
    int kz = k / 9, ky = (k % 9) / 3, kx = k % 3;
    float ox = (float)(kx - 1);
    float oy = (float)(ky - 1);
    float oz = (float)(kz - 2);
    const float* T = trans + n * 12;
    shifts[i*3+0] = T[0]*ox + T[1]*oy + T[2]*oz  + T[3]  + 63.5f;
    shifts[i*3+1] = T[4]*ox + T[5]*oy + T[6]*oz  + T[7]  + 63.5f;
    shifts[i*3+2] = T[8]*ox + T[9]*oy + T[10]*oz + T[11] + 63.5f;
}

// ---------------------------------------------------------------------------
// reduction helper (256-thread blocks)
__device__ __forceinline__ void block_reduce_add(double s, double* out)
{
    for (int o = 32; o > 0; o >>= 1) s += __shfl_down(s, o);
    __shared__ double ls[4];
    int lane = threadIdx.x & 63, wid = threadIdx.x >> 6;
    if (lane == 0) ls[wid] = s;
    __syncthreads();
    if (threadIdx.x == 0) atomicAdd(out, ls[0] + ls[1] + ls[2] + ls[3]);
}

// ---------------------------------------------------------------------------
// A-side: val[n,h,w] = sum_k w_k * trilerp(vol, R*base + shift_k)
// Also: zeroes ap_zero (grid-stride) and accumulates pAp = sum val^2 into pap.
__global__ __launch_bounds__(256) void k_gather(const float* __restrict__ vol,
                                                const float* __restrict__ shifts,
                                                const float* __restrict__ psf,
                                                const float* __restrict__ trans,
                                                float* __restrict__ val,
                                                float4* __restrict__ ap_zero,
                                                double* __restrict__ pap)
{
    __shared__ float sh[NK*4];
    int n = blockIdx.x >> 6, seg = blockIdx.x & 63, tid = threadIdx.x;

    // zero next AtA accumulator (completes before k_splat launch)
    int zi = blockIdx.x * 256 + tid;
    if (zi < NVOX/4) ap_zero[zi] = make_float4(0.f, 0.f, 0.f, 0.f);

    for (int i = tid; i < NK*3; i += 256) sh[i] = shifts[n*NK*3 + i];
    if (tid < NK) sh[NK*3+tid] = psf[tid];
    const float* T = trans + n*12;
    float R00=T[0],R01=T[1],R10=T[4],R11=T[5],R20=T[8],R21=T[9];
    __syncthreads();

    int idx = seg*256 + tid;
    int h = idx >> 7, w = idx & 127;
    float bx = ((float)w - 63.5f)*1.25f;
    float by = ((float)h - 63.5f)*1.25f;
    float rbx = R00*bx + R01*by;
    float rby = R10*bx + R11*by;
    float rbz = R20*bx + R21*by;

    float s = 0.f;
#pragma unroll 3
    for (int k = 0; k < NK; ++k)
        s += sh[NK*3+k] * trilerp_gather_g(vol, rbx + sh[k*3], rby + sh[k*3+1],
                                           rbz + sh[k*3+2]);
    val[n*16384 + idx] = s;

    block_reduce_add((double)s * (double)s, pap);
}

// ---------------------------------------------------------------------------
// At-side: one WAVE per 16x16 tile, LDS slab accumulator.
// Race-free non-atomic RMW via 4 checkerboard parity phases (active pixels in
// a phase differ by even pixel steps => projected 2x2x2 corner boxes of any
// two lanes are disjoint). Cross-phase/-tap RAW through LDS is safe because a
// wave's DS instructions execute in order (lgkmcnt in-order for DS) and the
// compiler cannot reorder potentially-aliasing ds accesses. Row stride padded
// to odd to spread banks.
__global__ __launch_bounds__(64) void k_splat(const float* __restrict__ val,
                                              float* __restrict__ pout,
                                              const float* __restrict__ shifts,
                                              const float* __restrict__ psf,
                                              const float* __restrict__ trans)
{
    __shared__ float tile[LDSF];
    __shared__ float sh[NK*4];
    int n = blockIdx.x >> 6, t2 = blockIdx.x & 63;
    int th = t2 >> 3, tw = t2 & 7;
    int lane = threadIdx.x;

    for (int i = lane; i < NK*3; i += 64) sh[i] = shifts[n*NK*3 + i];
    if (lane < NK) sh[NK*3+lane] = psf[lane];
    const float* T = trans + n*12;
    float R00=T[0],R01=T[1],R10=T[4],R11=T[5],R20=T[8],R21=T[9];
    __syncthreads();

    // AABB: lane-parallel min/max over the 45 tap shifts
    float sx0, sy0, sz0;
    if (lane < NK) { sx0 = sh[lane*3]; sy0 = sh[lane*3+1]; sz0 = sh[lane*3+2]; }
    else           { sx0 = sh[0];      sy0 = sh[1];        sz0 = sh[2]; }
    float sxmn=sx0,sxmx=sx0,symn=sy0,symx=sy0,szmn=sz0,szmx=sz0;
    for (int o = 32; o; o >>= 1) {
        sxmn = fminf(sxmn, __shfl_xor(sxmn,o)); sxmx = fmaxf(sxmx, __shfl_xor(sxmx,o));
        symn = fminf(symn, __shfl_xor(symn,o)); symx = fmaxf(symx, __shfl_xor(symx,o));
        szmn = fminf(szmn, __shfl_xor(szmn,o)); szmx = fmaxf(szmx, __shfl_xor(szmx,o));
    }
    float cbx = ((float)(tw*16) + 7.5f - 63.5f)*1.25f;
    float cby = ((float)(th*16) + 7.5f - 63.5f)*1.25f;
    const float hs = 9.375f;   // 7.5 * 1.25
    float cx = R00*cbx + R01*cby, hx = (fabsf(R00)+fabsf(R01))*hs;
    float cy = R10*cbx + R11*cby, hy = (fabsf(R10)+fabsf(R11))*hs;
    float cz = R20*cbx + R21*cby, hz = (fabsf(R20)+fabsf(R21))*hs;
    int x_lo = (int)floorf(cx-hx+sxmn), x_hi = (int)floorf(cx+hx+sxmx)+1;
    int y_lo = (int)floorf(cy-hy+symn), y_hi = (int)floorf(cy+hy+symx)+1;
    int z_lo = (int)floorf(cz-hz+szmn), z_hi = (int)floorf(cz+hz+szmx)+1;
    int dxs  = x_hi - x_lo + 1;
    dxs |= 1;                         // odd row stride -> fewer bank conflicts
    int dys  = y_hi - y_lo + 1;
    int dzs  = z_hi - z_lo + 1;
    int dxdy = dxs * dys;
    int total = dxdy * dzs;

    bool safe = (2.5f*(R00 - fabsf(R01)) >= 2.0f) &&
                (2.5f*(R11 - fabsf(R10)) >= 2.0f);

    if (total <= LDSF) {
        for (int c = lane; c < total; c += 64) tile[c] = 0.f;
        __syncthreads();

        // per-phase pixel geometry (fully unrolled -> registers)
        float prbx[4], prby[4], prbz[4], pval[4];
#pragma unroll
        for (int p = 0; p < 4; ++p) {
            int w = tw*16 + 2*(lane & 7)  + (p & 1);
            int h = th*16 + 2*(lane >> 3) + (p >> 1);
            float bx = ((float)w - 63.5f)*1.25f;
            float by = ((float)h - 63.5f)*1.25f;
            prbx[p] = R00*bx + R01*by;
            prby[p] = R10*bx + R11*by;
            prbz[p] = R20*bx + R21*by;
            pval[p] = val[n*16384 + (h<<7) + w];
        }

#pragma unroll 1
        for (int k = 0; k < NK; ++k) {
            float sx = sh[k*3], sy = sh[k*3+1], sz = sh[k*3+2], wk = sh[NK*3+k];
#pragma unroll
            for (int p = 0; p < 4; ++p) {
                float x = prbx[p] + sx, y = prby[p] + sy, z = prbz[p] + sz;
                float x0f = floorf(x), y0f = floorf(y), z0f = floorf(z);
                int lx = (int)x0f - x_lo, ly = (int)y0f - y_lo, lz = (int)z0f - z_lo;
                float fx = x - x0f, fy = y - y0f, fz = z - z0f;
                float vw = pval[p] * wk;
                float wx1 = fx, wx0 = 1.f - fx;
                float wy1 = fy, wy0 = 1.f - fy;
                float wz1 = fz, wz0 = 1.f - fz;
                float* q = tile + lz*dxdy + ly*dxs + lx;
                if (safe) {
                    q[0]          += vw*wz0*wy0*wx0;
                    q[1]          += vw*wz0*wy0*wx1;
                    q[dxs]        += vw*wz0*wy1*wx0;
                    q[dxs+1]      += vw*wz0*wy1*wx1;
                    q[dxdy]       += vw*wz1*wy0*wx0;
                    q[dxdy+1]     += vw*wz1*wy0*wx1;
                    q[dxdy+dxs]   += vw*wz1*wy1*wx0;
                    q[dxdy+dxs+1] += vw*wz1*wy1*wx1;
                } else {
                    atomicAdd(q,            vw*wz0*wy0*wx0);
                    atomicAdd(q+1,          vw*wz0*wy0*wx1);
                    atomicAdd(q+dxs,        vw*wz0*wy1*wx0);
                    atomicAdd(q+dxs+1,      vw*wz0*wy1*wx1);
                    atomicAdd(q+dxdy,       vw*wz1*wy0*wx0);
                    atomicAdd(q+dxdy+1,     vw*wz1*wy0*wx1);
                    atomicAdd(q+dxdy+dxs,   vw*wz1*wy1*wx0);
                    atomicAdd(q+dxdy+dxs+1, vw*wz1*wy1*wx1);
                }
            }
        }
        __syncthreads();

        for (int c = lane; c < total; c += 64) {
            float v2 = tile[c];
            if (v2 != 0.f) {
                int lz = c / dxdy;
                int rem = c - lz*dxdy;
                int ly = rem / dxs;
                int lx = rem - ly*dxs;
                int gx = x_lo+lx, gy = y_lo+ly, gz = z_lo+lz;
                if (((unsigned)gx < 128u) & ((unsigned)gy < 128u) & ((unsigned)gz < 128u))
                    unsafeAtomicAdd(pout + gz*16384 + gy*128 + gx, v2);
            }
        }
    } else {
        // fallback: direct global-atomic splat
        for (int s2 = 0; s2 < 4; ++s2) {
            int px = s2*64 + lane;
            int ty = px >> 4, tx = px & 15;
            int h = th*16 + ty, w = tw*16 + tx;
            float bx = ((float)w - 63.5f)*1.25f;
            float by = ((float)h - 63.5f)*1.25f;
            float rbx = R00*bx + R01*by;
            float rby = R10*bx + R11*by;
            float rbz = R20*bx + R21*by;
            float v = val[n*16384 + (h<<7) + w];
#pragma unroll 1
            for (int k = 0; k < NK; ++k)
                trilerp_splat_g(pout, rbx + sh[k*3], rby + sh[k*3+1],
                                rbz + sh[k*3+2], sh[NK*3+k] * v);
        }
    }
}

// ---------------------------------------------------------------------------
// CG vector updates
__global__ __launch_bounds__(256) void k_init(const float* __restrict__ b,
                                              const float* __restrict__ Ax,
                                              float* __restrict__ r,
                                              float* __restrict__ p,
                                              double* rr0)
{
    double s = 0.0;
    for (int i = blockIdx.x * blockDim.x + threadIdx.x; i < NVOX;
         i += gridDim.x * blockDim.x) {
        float rv = b[i] - Ax[i];
        r[i] = rv;
        p[i] = rv;
        s += (double)rv * (double)rv;
    }
    block_reduce_add(s, rr0);
}

__global__ __launch_bounds__(256) void k_update_xr(float* __restrict__ x,
                                                   float* __restrict__ r,
                                                   const float* __restrict__ p,
                                                   const float* __restrict__ Ap,
                                                   const double* rr, const double* pap,
                                                   double* rrn, int do_r)
{
    float alpha = (float)(rr[0] / pap[0]);
    double s = 0.0;
    for (int i = blockIdx.x * blockDim.x + threadIdx.x; i < NVOX;
         i += gridDim.x * blockDim.x) {
        x[i] += alpha * p[i];
        if (do_r) {
            float rn = r[i] - alpha * Ap[i];
            r[i] = rn;
            s += (double)rn * (double)rn;
        }
    }
    block_reduce_add(s, rrn);
}

__global__ __launch_bounds__(256) void k_update_p(float* __restrict__ p,
                                                  const float* __restrict__ r,
                                                  const double* rrn, const double* rro)
{
    float beta = (float)(rrn[0] / rro[0]);
    for (int i = blockIdx.x * blockDim.x + threadIdx.x; i < NVOX;
         i += gridDim.x * blockDim.x)
        p[i] = r[i] + beta * p[i];
}

__global__ __launch_bounds__(256) void k_relu(const float* __restrict__ x,
                                              float* __restrict__ out)
{
    for (int i = blockIdx.x * blockDim.x + threadIdx.x; i < NVOX;
         i += gridDim.x * blockDim.x)
        out[i] = fmaxf(x[i], 0.f);
}

// ---------------------------------------------------------------------------
extern "C" void kernel_launch(void* const* d_in, const int* in_sizes, int n_in,
                              void* d_out, int out_size, void* d_ws, size_t ws_size,
                              hipStream_t stream)
{
    const float* vol    = (const float*)d_in[0];   // 128^3
    const float* slices = (const float*)d_in[1];   // 48*128*128
    const float* trans  = (const float*)d_in[2];   // 48*3*4
    const float* psf    = (const float*)d_in[3];   // 45
    float* out = (float*)d_out;

    const size_t VB = (size_t)NVOX * 4;            // 8 MB
    char* w = (char*)d_ws;
    float* x      = (float*)(w);
    float* b      = (float*)(w + VB);
    float* r      = (float*)(w + VB*2);
    float* p      = (float*)(w + VB*3);
    float* Ap     = (float*)(w + VB*4);
    float* shifts = (float*)(w + VB*5);            // 25920 B
    double* sc    = (double*)(w + VB*5 + 32768);   // 22 doubles
    float* val    = (float*)(w + VB*6);            // 48*16384 floats = 3 MB
    // sc[0..10] = rr_i, sc[11..20] = pAp_i, sc[21] = dummy pAp for initial AtA

    hipMemsetAsync(sc, 0, 22 * sizeof(double), stream);
    hipLaunchKernelGGL(k_shifts, dim3(9), dim3(256), 0, stream, trans, shifts);

    // b = At(y): slices already have the val layout — splat directly
    hipMemsetAsync(b, 0, VB, stream);
    hipLaunchKernelGGL(k_splat, dim3(NSL * 64), dim3(64), 0, stream,
                       slices, b, shifts, psf, trans);

    // x = vol (initial guess)
    hipMemcpyAsync(x, vol, VB, hipMemcpyDeviceToDevice, stream);

    // Ax = AtA(x)  (k_gather zeroes Ap and computes a dummy pAp)
    hipLaunchKernelGGL(k_gather, dim3(NSL * 64), dim3(256), 0, stream,
                       x, shifts, psf, trans, val, (float4*)Ap, sc + 21);
    hipLaunchKernelGGL(k_splat, dim3(NSL * 64), dim3(64), 0, stream,
                       val, Ap, shifts, psf, trans);

    // r = b - Ax; p = r; rr0 = <r,r>
    hipLaunchKernelGGL(k_init, dim3(512), dim3(256), 0, stream, b, Ap, r, p, sc + 0);

    for (int i = 0; i < 10; ++i) {
        // gather: val = A p, Ap := 0, pAp_i = sum(val^2) == <p, AtA p>
        hipLaunchKernelGGL(k_gather, dim3(NSL * 64), dim3(256), 0, stream,
                           p, shifts, psf, trans, val, (float4*)Ap, sc + 11 + i);
        hipLaunchKernelGGL(k_splat, dim3(NSL * 64), dim3(64), 0, stream,
                           val, Ap, shifts, psf, trans);
        hipLaunchKernelGGL(k_update_xr, dim3(512), dim3(256), 0, stream,
                           x, r, p, Ap, sc + i, sc + 11 + i, sc + i + 1, (int)(i < 9));
        if (i < 9)
            hipLaunchKernelGGL(k_update_p, dim3(512), dim3(256), 0, stream,
                               p, r, sc + i + 1, sc + i);
    }

    hipLaunchKernelGGL(k_relu, dim3(512), dim3(256), 0, stream, x, out);
}